// Round 12
// baseline (3542.529 us; speedup 1.0000x reference)
//
#include <hip/hip_runtime.h>
#include <math.h>

namespace {
constexpr int cS = 64, cI = 128, cNO = 64, cK = 64, cD = 64, cB = 64, cT = 256;
constexpr float cTH = 0.01f;
constexpr int NTASK = cB * cT;
constexpr int NSPLIT = 16;                 // WGs per sequence
typedef float vf4 __attribute__((ext_vector_type(4)));

__device__ inline void st_agent(float* p, float v) {
    __hip_atomic_store(p, v, __ATOMIC_RELAXED, __HIP_MEMORY_SCOPE_AGENT);
}
__device__ inline float ld_agent(const float* p) {
    return __hip_atomic_load(p, __ATOMIC_RELAXED, __HIP_MEMORY_SCOPE_AGENT);
}

// ====== Phase 1: recurrence, 16 WGs/seq x 256 thr, 4 WGs/CU (cross-seq TLP) ======
__global__ __launch_bounds__(256, 4)
void p1_kernel(const int* __restrict__ seq,
               const float* __restrict__ Tm,     // (S,I,D,S)
               const float* __restrict__ pgate,  // (S,I,1)
               const float* __restrict__ qgate,  // (S,I,1)
               const float* __restrict__ pval,   // (S,I,D)
               const float* __restrict__ initl,  // (S,)
               float* __restrict__ stbuf,        // (B*T,128)
               int* __restrict__ cnt,            // (B*T) zeroed per launch
               float* __restrict__ gpart)        // (B,2,16,128)
{
    const int b  = blockIdx.x >> 4;
    const int jw = blockIdx.x & 15;
    const int tid = threadIdx.x;
    const int wave = tid >> 6, lane = tid & 63;
    const int dq = lane >> 4, o4 = lane & 15;
    const int srow = jw * 4 + wave;          // this wave's single s-row

    __shared__ float s_state[cS], s_stack[cD], s_pushv[cD], s_pvpart[cD];
    __shared__ float s_ptr[cK], s_w[cK];
    __shared__ float s_content[cK][cD];
    __shared__ float s_redA[4][64], s_redB[4][64], s_npart[4][64];
    __shared__ int   s_seq[cT];
    __shared__ float s_push, s_pop;

    if (wave == 0) {
        float v = initl[lane];
        float m = v;
        #pragma unroll
        for (int sh = 1; sh < 64; sh <<= 1) m = fmaxf(m, __shfl_xor(m, sh));
        float e = expf(v - m);
        float s = e;
        #pragma unroll
        for (int sh = 1; sh < 64; sh <<= 1) s += __shfl_xor(s, sh);
        s_state[lane] = e / s;
    } else if (wave == 1) {
        s_ptr[lane] = (lane == 0) ? 1.0f : 0.0f;
    }
    for (int i = tid; i < cK * cD; i += 256) (&s_content[0][0])[i] = 0.f;
    s_seq[tid] = seq[b * cT + tid];
    __syncthreads();

    for (int t = 0; t < cT; ++t) {
        const int inp = s_seq[t];

        // ---- A1: stack_top partials (16 k-rows/wave) + push_v partial (1 s-row/wave) ----
        {
            float accA = 0.f;
            #pragma unroll
            for (int j = 0; j < 16; ++j) {
                int k = wave * 16 + j;
                accA += s_ptr[k] * s_content[k][lane];
            }
            float accB = s_state[srow] * pval[((size_t)srow * cI + inp) * cD + lane];
            s_redA[wave][lane] = accA;
            s_redB[wave][lane] = accB;
        }
        __syncthreads();

        // ---- A2: finalize stack_top; gates; stash pv partial; publish stbuf ----
        float* sb = stbuf + (size_t)(b * cT + t) * 128;
        if (wave == 0) {
            float a = s_redA[0][lane] + s_redA[1][lane] + s_redA[2][lane] + s_redA[3][lane];
            s_stack[lane] = a;
            if (jw == 0) { sb[lane] = a; sb[64 + lane] = s_state[lane]; }
        } else if (wave == 1) {
            s_pvpart[lane] = s_redB[0][lane] + s_redB[1][lane] + s_redB[2][lane] + s_redB[3][lane];
        } else if (wave == 2) {
            float v = pgate[lane * cI + inp] * s_state[lane];
            #pragma unroll
            for (int sh = 1; sh < 64; sh <<= 1) v += __shfl_xor(v, sh);
            if (lane == 0) s_push = 1.0f / (1.0f + expf(-v));
        } else {
            float v = qgate[lane * cI + inp] * s_state[lane];
            #pragma unroll
            for (int sh = 1; sh < 64; sh <<= 1) v += __shfl_xor(v, sh);
            if (lane == 0) s_pop = 1.0f / (1.0f + expf(-v));
        }
        __syncthreads();

        // ---- B: this wave's single T-row (16 float4 loads in flight) ----
        {
            float xs[16];
            #pragma unroll
            for (int i = 0; i < 16; ++i) xs[i] = s_stack[dq * 16 + i];

            const vf4* rp = reinterpret_cast<const vf4*>(
                Tm + (size_t)(srow * cI + inp) * (cD * cS)) + o4;
            vf4 va[16];
            #pragma unroll
            for (int i = 0; i < 16; ++i) va[i] = rp[(dq * 16 + i) * 16];

            vf4 a;
            a.x = 0.f; a.y = 0.f; a.z = 0.f; a.w = 0.f;
            #pragma unroll
            for (int i = 0; i < 16; ++i) {
                float x = xs[i];
                a.x = fmaf(x, va[i].x, a.x); a.y = fmaf(x, va[i].y, a.y);
                a.z = fmaf(x, va[i].z, a.z); a.w = fmaf(x, va[i].w, a.w);
            }
            #pragma unroll
            for (int m = 16; m < 64; m <<= 1) {
                a.x += __shfl_xor(a.x, m); a.y += __shfl_xor(a.y, m);
                a.z += __shfl_xor(a.z, m); a.w += __shfl_xor(a.w, m);
            }
            float mx = fmaxf(fmaxf(a.x, a.y), fmaxf(a.z, a.w));
            #pragma unroll
            for (int m = 1; m < 16; m <<= 1) mx = fmaxf(mx, __shfl_xor(mx, m));
            vf4 e;
            e.x = expf(a.x - mx); e.y = expf(a.y - mx);
            e.z = expf(a.z - mx); e.w = expf(a.w - mx);
            float sm = e.x + e.y + e.z + e.w;
            #pragma unroll
            for (int m = 1; m < 16; m <<= 1) sm += __shfl_xor(sm, m);
            float coef = s_state[srow] / sm;
            vf4 nacc;
            nacc.x = coef * e.x;
            nacc.y = coef * e.y;
            nacc.z = coef * e.z;
            nacc.w = coef * e.w;
            if (dq == 0) {
                s_npart[wave][o4 * 4 + 0] = nacc.x;
                s_npart[wave][o4 * 4 + 1] = nacc.y;
                s_npart[wave][o4 * 4 + 2] = nacc.z;
                s_npart[wave][o4 * 4 + 3] = nacc.w;
            }
        }
        __syncthreads();

        // ---- C: wave0 = publish/flag/poll/combine; wave1 = pointer pop+push ----
        if (wave == 0) {
            float* gq = gpart + ((size_t)(b * 2 + (t & 1)) * NSPLIT + jw) * 128;
            float np = s_npart[0][lane] + s_npart[1][lane] + s_npart[2][lane] + s_npart[3][lane];
            st_agent(gq + lane, np);
            st_agent(gq + 64 + lane, s_pvpart[lane]);
            asm volatile("s_waitcnt vmcnt(0)" ::: "memory");
            int* c = cnt + b * cT + t;
            if (lane == 0)
                __hip_atomic_fetch_add(c, 1, __ATOMIC_RELAXED, __HIP_MEMORY_SCOPE_AGENT);
            while (__hip_atomic_load(c, __ATOMIC_RELAXED, __HIP_MEMORY_SCOPE_AGENT) < NSPLIT) {}
            const float* gb = gpart + (size_t)(b * 2 + (t & 1)) * NSPLIT * 128;
            float ns = 0.f, pvs = 0.f;
            #pragma unroll
            for (int q = 0; q < NSPLIT; ++q) {
                ns  += ld_agent(gb + q * 128 + lane);
                pvs += ld_agent(gb + q * 128 + 64 + lane);
            }
            s_state[lane] = ns;
            s_pushv[lane] = tanhf(pvs);
        } else if (wave == 1) {
            float p  = s_ptr[lane];
            float sd = (lane < cK - 1) ? s_ptr[lane + 1] : 0.f;
            float pop = s_pop;
            float ppo = pop * sd + (1.f - pop) * p;
            float p2  = (pop > cTH) ? ppo : p;
            float su  = __shfl_up(p2, 1);
            if (lane == 0) su = 0.f;
            float push = s_push;
            float ppu = push * su + (1.f - push) * p2;
            s_w[lane] = ppu;
            s_ptr[lane] = (push > cTH) ? ppu : p2;
        }
        __syncthreads();

        // ---- C3: content update (uniform branch, identical across WGs) ----
        if (s_push > cTH) {
            #pragma unroll
            for (int it = 0; it < 16; ++it) {
                int idx = tid + it * 256;
                int k = idx >> 6, d = idx & 63;
                float w = s_w[k];
                s_content[k][d] = s_content[k][d] * (1.f - w) + s_pushv[d] * w;
            }
        }
        __syncthreads();
    }
}

// =================== Binning: group (b,t) tasks by symbol ===================
__global__ void k_count(const int* __restrict__ seq, int* __restrict__ counts) {
    int i = blockIdx.x * 256 + threadIdx.x;
    if (i < NTASK) atomicAdd(&counts[seq[i]], 1);
}
__global__ void k_scan(const int* __restrict__ counts, int* __restrict__ offsets,
                       int* __restrict__ cursor) {
    const int lane = threadIdx.x & 63;
    int c0 = counts[lane], c1 = counts[64 + lane];
    int s0 = c0, s1 = c1;
    #pragma unroll
    for (int m = 1; m < 64; m <<= 1) {
        int t0 = __shfl_up(s0, m);
        int t1 = __shfl_up(s1, m);
        if (lane >= m) { s0 += t0; s1 += t1; }
    }
    int tot0 = __shfl(s0, 63);
    int e0 = s0 - c0;
    int e1 = tot0 + s1 - c1;
    offsets[lane] = e0;       cursor[lane] = e0;
    offsets[64 + lane] = e1;  cursor[64 + lane] = e1;
    if (lane == 63) offsets[128] = tot0 + __shfl(s1, 63);
}
__global__ void k_scatter(const int* __restrict__ seq, int* __restrict__ cursor,
                          int* __restrict__ tasks) {
    int i = blockIdx.x * 256 + threadIdx.x;
    if (i < NTASK) {
        int pos = atomicAdd(&cursor[seq[i]], 1);
        tasks[pos] = i;
    }
}

// ====== Phase 2: output head. LDS-staged O rows, NT loads, 8 tasks/wave ======
__global__ __launch_bounds__(512, 2)
void p2_kernel(const float* __restrict__ Om,      // (S,I,D,NO)
               const float* __restrict__ stbuf,   // (B*T,128)
               const int* __restrict__ offsets,   // (129,)
               const int* __restrict__ tasks,     // (B*T,)
               float* __restrict__ out)           // (B*T,NO)
{
    const int g = blockIdx.x >> 1, h = blockIdx.x & 1;
    const int tid = threadIdx.x, wave = tid >> 6, lane = tid & 63;
    const int dq = lane >> 4, o4 = lane & 15;

    const int beg = offsets[g], end = offsets[g + 1];
    const int n = end - beg, half = (n + 1) >> 1;
    const int hbeg = beg + h * half;
    const int hend = h ? end : (beg + half);
    const int cnt = hend - hbeg;
    if (cnt <= 0) return;
    const int nsweep = (cnt + 63) >> 6;

    __shared__ vf4 sO[2][1024];

    const vf4* O0 = reinterpret_cast<const vf4*>(Om) + (size_t)g * 1024;
    const size_t rowstride = (size_t)cI * 1024;

    for (int sweep = 0; sweep < nsweep; ++sweep) {
        int   tsk[8];
        bool  val[8];
        float stv[8][16];
        float sstate[8];
        vf4   acc[8];
        #pragma unroll
        for (int u = 0; u < 8; ++u) {
            int idx = hbeg + sweep * 64 + (u >> 2) * 32 + wave * 4 + (u & 3);
            bool v = idx < hend;
            val[u] = v;
            int id = tasks[v ? idx : hbeg];
            id = __builtin_amdgcn_readfirstlane(id);
            tsk[u] = id;
            const float* sp = stbuf + (size_t)id * 128;
            #pragma unroll
            for (int i = 0; i < 16; ++i) stv[u][i] = sp[dq * 16 + i];
            sstate[u] = sp[64 + lane];
            acc[u].x = 0.f; acc[u].y = 0.f; acc[u].z = 0.f; acc[u].w = 0.f;
        }

        vf4 r0 = __builtin_nontemporal_load(O0 + (size_t)tid * 2);
        vf4 r1 = __builtin_nontemporal_load(O0 + (size_t)tid * 2 + 1);

        for (int s = 0; s < cS; ++s) {
            sO[s & 1][tid * 2]     = r0;
            sO[s & 1][tid * 2 + 1] = r1;
            __syncthreads();
            if (s + 1 < cS) {
                const vf4* nr = O0 + (size_t)(s + 1) * rowstride;
                r0 = __builtin_nontemporal_load(nr + (size_t)tid * 2);
                r1 = __builtin_nontemporal_load(nr + (size_t)tid * 2 + 1);
            }
            vf4 part[8];
            #pragma unroll
            for (int u = 0; u < 8; ++u) { part[u].x = 0.f; part[u].y = 0.f; part[u].z = 0.f; part[u].w = 0.f; }
            #pragma unroll
            for (int i = 0; i < 16; ++i) {
                vf4 ovi = sO[s & 1][(dq * 16 + i) * 16 + o4];
                #pragma unroll
                for (int u = 0; u < 8; ++u) {
                    float x = stv[u][i];
                    part[u].x = fmaf(x, ovi.x, part[u].x);
                    part[u].y = fmaf(x, ovi.y, part[u].y);
                    part[u].z = fmaf(x, ovi.z, part[u].z);
                    part[u].w = fmaf(x, ovi.w, part[u].w);
                }
            }
            #pragma unroll
            for (int u = 0; u < 8; ++u) {
                vf4 a = part[u];
                #pragma unroll
                for (int m = 16; m < 64; m <<= 1) {
                    a.x += __shfl_xor(a.x, m); a.y += __shfl_xor(a.y, m);
                    a.z += __shfl_xor(a.z, m); a.w += __shfl_xor(a.w, m);
                }
                float mx = fmaxf(fmaxf(a.x, a.y), fmaxf(a.z, a.w));
                #pragma unroll
                for (int m = 1; m < 16; m <<= 1) mx = fmaxf(mx, __shfl_xor(mx, m));
                vf4 e;
                e.x = expf(a.x - mx); e.y = expf(a.y - mx);
                e.z = expf(a.z - mx); e.w = expf(a.w - mx);
                float sm = e.x + e.y + e.z + e.w;
                #pragma unroll
                for (int m = 1; m < 16; m <<= 1) sm += __shfl_xor(sm, m);
                float coef = __shfl(sstate[u], s) / sm;
                acc[u].x = fmaf(coef, e.x, acc[u].x);
                acc[u].y = fmaf(coef, e.y, acc[u].y);
                acc[u].z = fmaf(coef, e.z, acc[u].z);
                acc[u].w = fmaf(coef, e.w, acc[u].w);
            }
        }
        #pragma unroll
        for (int u = 0; u < 8; ++u) {
            if (val[u] && dq == 0) {
                float* op = out + (size_t)tsk[u] * cNO + o4 * 4;
                op[0] = acc[u].x; op[1] = acc[u].y; op[2] = acc[u].z; op[3] = acc[u].w;
            }
        }
    }
}

// =================== Fallback: monolithic (if ws too small) ===================
__global__ __launch_bounds__(512, 1)
void fpt_mono(const int* __restrict__ seq, const float* __restrict__ Tm,
              const float* __restrict__ Om, const float* __restrict__ pgate,
              const float* __restrict__ qgate, const float* __restrict__ pval,
              const float* __restrict__ initl, float* __restrict__ out)
{
    const int b = blockIdx.x;
    const int tid = threadIdx.x;
    const int wave = tid >> 6, lane = tid & 63;
    const int dq = lane >> 4, o4 = lane & 15;

    __shared__ float s_state[cS], s_nstate[cS], s_stack[cD], s_pushv[cD];
    __shared__ float s_ptr[cK], s_ptr2[cK], s_w[cK];
    __shared__ float s_content[cK][cD];
    __shared__ float s_redA[8][64], s_redB[8][64];
    __shared__ float s_opart[4][cNO], s_npart[4][cS];
    __shared__ float s_push, s_pop;

    if (wave == 0) {
        float v = initl[lane];
        float m = v;
        #pragma unroll
        for (int sh = 1; sh < 64; sh <<= 1) m = fmaxf(m, __shfl_xor(m, sh));
        float e = expf(v - m);
        float s = e;
        #pragma unroll
        for (int sh = 1; sh < 64; sh <<= 1) s += __shfl_xor(s, sh);
        s_state[lane] = e / s;
    } else if (wave == 1) s_ptr[lane] = (lane == 0) ? 1.0f : 0.0f;
    for (int idx = tid; idx < cK * cD; idx += 512) (&s_content[0][0])[idx] = 0.0f;
    __syncthreads();

    for (int t = 0; t < cT; ++t) {
        const int inp = seq[b * cT + t];
        {
            float accA = 0.f, accB = 0.f;
            #pragma unroll
            for (int j = 0; j < 8; ++j) {
                int k = wave * 8 + j;
                accA += s_ptr[k] * s_content[k][lane];
                accB += s_state[k] * pval[(k * cI + inp) * cD + lane];
            }
            s_redA[wave][lane] = accA;
            s_redB[wave][lane] = accB;
        }
        __syncthreads();
        if (wave == 0) {
            float a = 0.f;
            #pragma unroll
            for (int g = 0; g < 8; ++g) a += s_redA[g][lane];
            s_stack[lane] = a;
        } else if (wave == 1) {
            float a = 0.f;
            #pragma unroll
            for (int g = 0; g < 8; ++g) a += s_redB[g][lane];
            s_pushv[lane] = tanhf(a);
        } else if (wave == 2) {
            float v = pgate[lane * cI + inp] * s_state[lane];
            #pragma unroll
            for (int sh = 1; sh < 64; sh <<= 1) v += __shfl_xor(v, sh);
            if (lane == 0) s_push = 1.0f / (1.0f + expf(-v));
        } else if (wave == 3) {
            float v = qgate[lane * cI + inp] * s_state[lane];
            #pragma unroll
            for (int sh = 1; sh < 64; sh <<= 1) v += __shfl_xor(v, sh);
            if (lane == 0) s_pop = 1.0f / (1.0f + expf(-v));
        }
        __syncthreads();
        {
            const bool isO = (wave < 4);
            const int w4 = wave & 3;
            const float* Mbase = isO ? Om : Tm;
            float xs[16];
            #pragma unroll
            for (int i = 0; i < 16; ++i) xs[i] = s_stack[dq * 16 + i];
            float4 oacc = make_float4(0.f, 0.f, 0.f, 0.f);
            for (int r = 0; r < 16; ++r) {
                const int s = w4 * 16 + r;
                const float4* rowp =
                    reinterpret_cast<const float4*>(Mbase + (size_t)(s * cI + inp) * (cD * 64)) + o4;
                float4 acc = make_float4(0.f, 0.f, 0.f, 0.f);
                #pragma unroll
                for (int i = 0; i < 16; ++i) {
                    float4 mv = rowp[(dq * 16 + i) * 16];
                    float xd = xs[i];
                    acc.x = fmaf(xd, mv.x, acc.x); acc.y = fmaf(xd, mv.y, acc.y);
                    acc.z = fmaf(xd, mv.z, acc.z); acc.w = fmaf(xd, mv.w, acc.w);
                }
                #pragma unroll
                for (int m = 16; m < 64; m <<= 1) {
                    acc.x += __shfl_xor(acc.x, m); acc.y += __shfl_xor(acc.y, m);
                    acc.z += __shfl_xor(acc.z, m); acc.w += __shfl_xor(acc.w, m);
                }
                float mx = fmaxf(fmaxf(acc.x, acc.y), fmaxf(acc.z, acc.w));
                #pragma unroll
                for (int m = 1; m < 16; m <<= 1) mx = fmaxf(mx, __shfl_xor(mx, m));
                float4 e;
                e.x = expf(acc.x - mx); e.y = expf(acc.y - mx);
                e.z = expf(acc.z - mx); e.w = expf(acc.w - mx);
                float sm = e.x + e.y + e.z + e.w;
                #pragma unroll
                for (int m = 1; m < 16; m <<= 1) sm += __shfl_xor(sm, m);
                float coef = s_state[s] / sm;
                oacc.x = fmaf(coef, e.x, oacc.x); oacc.y = fmaf(coef, e.y, oacc.y);
                oacc.z = fmaf(coef, e.z, oacc.z); oacc.w = fmaf(coef, e.w, oacc.w);
            }
            if (dq == 0) {
                float* dst = isO ? &s_opart[w4][0] : &s_npart[w4][0];
                dst[o4 * 4 + 0] = oacc.x; dst[o4 * 4 + 1] = oacc.y;
                dst[o4 * 4 + 2] = oacc.z; dst[o4 * 4 + 3] = oacc.w;
            }
        }
        __syncthreads();
        if (wave == 0) {
            float o = s_opart[0][lane] + s_opart[1][lane] + s_opart[2][lane] + s_opart[3][lane];
            out[((size_t)b * cT + t) * cNO + lane] = o;
        } else if (wave == 1) {
            s_nstate[lane] = s_npart[0][lane] + s_npart[1][lane] + s_npart[2][lane] + s_npart[3][lane];
        } else if (wave == 2) {
            float p = s_ptr[lane];
            float sd = (lane < cK - 1) ? s_ptr[lane + 1] : 0.f;
            float pop = s_pop;
            float pp = pop * sd + (1.f - pop) * p;
            s_ptr2[lane] = (pop > cTH) ? pp : p;
        }
        __syncthreads();
        if (wave == 0) {
            float p2 = s_ptr2[lane];
            float su = (lane > 0) ? s_ptr2[lane - 1] : 0.f;
            float push = s_push;
            float pp = push * su + (1.f - push) * p2;
            s_w[lane] = pp;
            s_ptr[lane] = (push > cTH) ? pp : p2;
        } else if (wave == 1) {
            s_state[lane] = s_nstate[lane];
        }
        __syncthreads();
        if (s_push > cTH) {
            for (int idx = tid; idx < cK * cD; idx += 512) {
                int k = idx >> 6, d = idx & 63;
                float w = s_w[k];
                s_content[k][d] = s_content[k][d] * (1.f - w) + s_pushv[d] * w;
            }
        }
        __syncthreads();
    }
}
} // namespace

extern "C" void kernel_launch(void* const* d_in, const int* in_sizes, int n_in,
                              void* d_out, int out_size, void* d_ws, size_t ws_size,
                              hipStream_t stream) {
    const int*   seq = (const int*)d_in[0];
    const float* Tm  = (const float*)d_in[1];
    const float* Om  = (const float*)d_in[2];
    const float* pg  = (const float*)d_in[3];
    const float* qg  = (const float*)d_in[4];
    const float* pv  = (const float*)d_in[5];
    const float* il  = (const float*)d_in[6];
    float* o = (float*)d_out;

    const size_t stbuf_bytes  = (size_t)NTASK * 128 * sizeof(float);   // 8 MB
    const size_t counts_off   = stbuf_bytes;
    const size_t offsets_off  = counts_off + 128 * sizeof(int);
    const size_t cursor_off   = offsets_off + 132 * sizeof(int);
    const size_t tasks_off    = cursor_off + 128 * sizeof(int);
    const size_t cnt_off      = tasks_off + (size_t)NTASK * sizeof(int);
    const size_t gpart_off    = cnt_off + (size_t)NTASK * sizeof(int);
    const size_t need         = gpart_off + (size_t)cB * 2 * NSPLIT * 128 * sizeof(float);

    if (ws_size < need) {
        hipLaunchKernelGGL(fpt_mono, dim3(cB), dim3(512), 0, stream,
                           seq, Tm, Om, pg, qg, pv, il, o);
        return;
    }

    float* stbuf  = (float*)d_ws;
    int* counts   = (int*)((char*)d_ws + counts_off);
    int* offsets  = (int*)((char*)d_ws + offsets_off);
    int* cursor   = (int*)((char*)d_ws + cursor_off);
    int* tasks    = (int*)((char*)d_ws + tasks_off);
    int* cnt      = (int*)((char*)d_ws + cnt_off);
    float* gpart  = (float*)((char*)d_ws + gpart_off);

    hipMemsetAsync(counts, 0, 128 * sizeof(int), stream);
    hipMemsetAsync(cnt, 0, (size_t)NTASK * sizeof(int), stream);
    hipLaunchKernelGGL(k_count,   dim3(NTASK / 256), dim3(256), 0, stream, seq, counts);
    hipLaunchKernelGGL(k_scan,    dim3(1),           dim3(64),  0, stream, counts, offsets, cursor);
    hipLaunchKernelGGL(k_scatter, dim3(NTASK / 256), dim3(256), 0, stream, seq, cursor, tasks);
    hipLaunchKernelGGL(p1_kernel, dim3(cB * NSPLIT), dim3(256), 0, stream,
                       seq, Tm, pg, qg, pv, il, stbuf, cnt, gpart);
    hipLaunchKernelGGL(p2_kernel, dim3(256), dim3(512), 0, stream, Om, stbuf, offsets, tasks, o);
}

// Round 13
// 2800.242 us; speedup vs baseline: 1.2651x; 1.2651x over previous
//
#include <hip/hip_runtime.h>
#include <math.h>

namespace {
constexpr int cS = 64, cI = 128, cNO = 64, cK = 64, cD = 64, cB = 64, cT = 256;
constexpr float cTH = 0.01f;
constexpr int NTASK = cB * cT;
constexpr int NSPLIT = 8;                  // WGs per sequence (R11 optimum)
typedef float vf4 __attribute__((ext_vector_type(4)));

__device__ inline void st_agent(float* p, float v) {
    __hip_atomic_store(p, v, __ATOMIC_RELAXED, __HIP_MEMORY_SCOPE_AGENT);
}
__device__ inline float ld_agent(const float* p) {
    return __hip_atomic_load(p, __ATOMIC_RELAXED, __HIP_MEMORY_SCOPE_AGENT);
}

// ====== Phase 1: recurrence, 8 WGs/seq x 256 thr, 2 WGs/CU.
//        Sync (poll+combine of new_state) overlapped with local work:
//        pushv/gates/pointer/content are computed locally per WG. ======
__global__ __launch_bounds__(256, 2)
void p1_kernel(const int* __restrict__ seq,
               const float* __restrict__ Tm,     // (S,I,D,S)
               const float* __restrict__ pgate,  // (S,I,1)
               const float* __restrict__ qgate,  // (S,I,1)
               const float* __restrict__ pval,   // (S,I,D)
               const float* __restrict__ initl,  // (S,)
               float* __restrict__ stbuf,        // (B*T,128)
               int* __restrict__ cnt,            // (B*T) zeroed per launch
               float* __restrict__ gpart)        // (B,2,8,64)
{
    const int b  = blockIdx.x >> 3;
    const int jw = blockIdx.x & 7;
    const int tid = threadIdx.x;
    const int wave = tid >> 6, lane = tid & 63;
    const int dq = lane >> 4, o4 = lane & 15;

    __shared__ float s_state[cS], s_stack[cD], s_pushv[cD];
    __shared__ float s_ptr[cK], s_w[cK];
    __shared__ float s_content[cK][cD];
    __shared__ float s_redA[4][64], s_redB[4][64], s_npart[4][64];
    __shared__ int   s_seq[cT];
    __shared__ float s_push, s_pop;

    if (wave == 0) {
        float v = initl[lane];
        float m = v;
        #pragma unroll
        for (int sh = 1; sh < 64; sh <<= 1) m = fmaxf(m, __shfl_xor(m, sh));
        float e = expf(v - m);
        float s = e;
        #pragma unroll
        for (int sh = 1; sh < 64; sh <<= 1) s += __shfl_xor(s, sh);
        s_state[lane] = e / s;
    } else if (wave == 1) {
        s_ptr[lane] = (lane == 0) ? 1.0f : 0.0f;
    }
    for (int i = tid; i < cK * cD; i += 256) (&s_content[0][0])[i] = 0.f;
    s_seq[tid] = seq[b * cT + tid];
    __syncthreads();

    for (int t = 0; t < cT; ++t) {
        const int inp = s_seq[t];

        // ---- P1a: waves1-3 compute stack_top partial groups (local);
        //           wave0 polls + combines new_state from step t-1 ----
        if (wave == 0) {
            if (t > 0) {
                int* c = cnt + b * cT + (t - 1);
                while (__hip_atomic_load(c, __ATOMIC_RELAXED, __HIP_MEMORY_SCOPE_AGENT) < NSPLIT) {}
                const float* gb = gpart + (size_t)(b * 2 + ((t - 1) & 1)) * NSPLIT * 64;
                float ns = 0.f;
                #pragma unroll
                for (int q = 0; q < NSPLIT; ++q) ns += ld_agent(gb + q * 64 + lane);
                s_state[lane] = ns;
            }
        } else if (wave == 1) {
            float a0 = 0.f, a1 = 0.f;
            #pragma unroll
            for (int j = 0; j < 16; ++j) a0 += s_ptr[j] * s_content[j][lane];
            #pragma unroll
            for (int j = 0; j < 16; ++j) a1 += s_ptr[16 + j] * s_content[16 + j][lane];
            s_redA[0][lane] = a0;
            s_redA[1][lane] = a1;
        } else if (wave == 2) {
            float a2 = 0.f;
            #pragma unroll
            for (int j = 0; j < 16; ++j) a2 += s_ptr[32 + j] * s_content[32 + j][lane];
            s_redA[2][lane] = a2;
        } else {
            float a3 = 0.f;
            #pragma unroll
            for (int j = 0; j < 16; ++j) a3 += s_ptr[48 + j] * s_content[48 + j][lane];
            s_redA[3][lane] = a3;
        }
        __syncthreads();

        // ---- P1b: all waves: pv partials (16 rows each, FULL pushv locally);
        //           waves2/3: gates; jw0-wave0: publish state to stbuf ----
        {
            float accB = 0.f;
            #pragma unroll
            for (int j = 0; j < 16; ++j) {
                int k = wave * 16 + j;
                accB += s_state[k] * pval[((size_t)k * cI + inp) * cD + lane];
            }
            s_redB[wave][lane] = accB;
        }
        if (wave == 2) {
            float v = pgate[lane * cI + inp] * s_state[lane];
            #pragma unroll
            for (int sh = 1; sh < 64; sh <<= 1) v += __shfl_xor(v, sh);
            if (lane == 0) s_push = 1.0f / (1.0f + expf(-v));
        } else if (wave == 3) {
            float v = qgate[lane * cI + inp] * s_state[lane];
            #pragma unroll
            for (int sh = 1; sh < 64; sh <<= 1) v += __shfl_xor(v, sh);
            if (lane == 0) s_pop = 1.0f / (1.0f + expf(-v));
        }
        float* sb = stbuf + (size_t)(b * cT + t) * 128;
        if (jw == 0 && wave == 0) sb[64 + lane] = s_state[lane];
        __syncthreads();

        // ---- P2: wave0: finalize stack_top (+publish); wave1: pushv=tanh(sum) ----
        if (wave == 0) {
            float a = s_redA[0][lane] + s_redA[1][lane] + s_redA[2][lane] + s_redA[3][lane];
            s_stack[lane] = a;
            if (jw == 0) sb[lane] = a;
        } else if (wave == 1) {
            s_pushv[lane] = tanhf(s_redB[0][lane] + s_redB[1][lane] +
                                  s_redB[2][lane] + s_redB[3][lane]);
        }
        __syncthreads();

        // ---- P3 (B): this wave's 2 T-rows (32 float4 loads in flight) ----
        {
            float xs[16];
            #pragma unroll
            for (int i = 0; i < 16; ++i) xs[i] = s_stack[dq * 16 + i];

            const int sA = jw * 8 + wave * 2;
            const int sB = sA + 1;
            const vf4* rpA = reinterpret_cast<const vf4*>(
                Tm + (size_t)(sA * cI + inp) * (cD * cS)) + o4;
            const vf4* rpB = reinterpret_cast<const vf4*>(
                Tm + (size_t)(sB * cI + inp) * (cD * cS)) + o4;
            vf4 va[16], vb[16];
            #pragma unroll
            for (int i = 0; i < 16; ++i) {
                va[i] = rpA[(dq * 16 + i) * 16];
                vb[i] = rpB[(dq * 16 + i) * 16];
            }
            vf4 aA, aB;
            aA.x = 0.f; aA.y = 0.f; aA.z = 0.f; aA.w = 0.f;
            aB.x = 0.f; aB.y = 0.f; aB.z = 0.f; aB.w = 0.f;
            #pragma unroll
            for (int i = 0; i < 16; ++i) {
                float x = xs[i];
                aA.x = fmaf(x, va[i].x, aA.x); aA.y = fmaf(x, va[i].y, aA.y);
                aA.z = fmaf(x, va[i].z, aA.z); aA.w = fmaf(x, va[i].w, aA.w);
                aB.x = fmaf(x, vb[i].x, aB.x); aB.y = fmaf(x, vb[i].y, aB.y);
                aB.z = fmaf(x, vb[i].z, aB.z); aB.w = fmaf(x, vb[i].w, aB.w);
            }
            #pragma unroll
            for (int m = 16; m < 64; m <<= 1) {
                aA.x += __shfl_xor(aA.x, m); aA.y += __shfl_xor(aA.y, m);
                aA.z += __shfl_xor(aA.z, m); aA.w += __shfl_xor(aA.w, m);
                aB.x += __shfl_xor(aB.x, m); aB.y += __shfl_xor(aB.y, m);
                aB.z += __shfl_xor(aB.z, m); aB.w += __shfl_xor(aB.w, m);
            }
            float mA = fmaxf(fmaxf(aA.x, aA.y), fmaxf(aA.z, aA.w));
            float mB = fmaxf(fmaxf(aB.x, aB.y), fmaxf(aB.z, aB.w));
            #pragma unroll
            for (int m = 1; m < 16; m <<= 1) {
                mA = fmaxf(mA, __shfl_xor(mA, m));
                mB = fmaxf(mB, __shfl_xor(mB, m));
            }
            vf4 eA, eB;
            eA.x = expf(aA.x - mA); eA.y = expf(aA.y - mA);
            eA.z = expf(aA.z - mA); eA.w = expf(aA.w - mA);
            eB.x = expf(aB.x - mB); eB.y = expf(aB.y - mB);
            eB.z = expf(aB.z - mB); eB.w = expf(aB.w - mB);
            float smA = eA.x + eA.y + eA.z + eA.w;
            float smB = eB.x + eB.y + eB.z + eB.w;
            #pragma unroll
            for (int m = 1; m < 16; m <<= 1) {
                smA += __shfl_xor(smA, m);
                smB += __shfl_xor(smB, m);
            }
            float cA = s_state[sA] / smA;
            float cB = s_state[sB] / smB;
            vf4 nacc;
            nacc.x = cA * eA.x + cB * eB.x;
            nacc.y = cA * eA.y + cB * eB.y;
            nacc.z = cA * eA.z + cB * eB.z;
            nacc.w = cA * eA.w + cB * eB.w;
            if (dq == 0) {
                s_npart[wave][o4 * 4 + 0] = nacc.x;
                s_npart[wave][o4 * 4 + 1] = nacc.y;
                s_npart[wave][o4 * 4 + 2] = nacc.z;
                s_npart[wave][o4 * 4 + 3] = nacc.w;
            }
        }
        __syncthreads();

        // ---- P4: wave0: publish np partial + flag; wave1: pointer pop+push ----
        if (wave == 0) {
            float* gq = gpart + ((size_t)(b * 2 + (t & 1)) * NSPLIT + jw) * 64;
            float np = s_npart[0][lane] + s_npart[1][lane] + s_npart[2][lane] + s_npart[3][lane];
            st_agent(gq + lane, np);
            asm volatile("s_waitcnt vmcnt(0)" ::: "memory");
            if (lane == 0)
                __hip_atomic_fetch_add(cnt + b * cT + t, 1, __ATOMIC_RELAXED, __HIP_MEMORY_SCOPE_AGENT);
        } else if (wave == 1) {
            float p  = s_ptr[lane];
            float sd = (lane < cK - 1) ? s_ptr[lane + 1] : 0.f;
            float pop = s_pop;
            float ppo = pop * sd + (1.f - pop) * p;
            float p2  = (pop > cTH) ? ppo : p;
            float su  = __shfl_up(p2, 1);
            if (lane == 0) su = 0.f;
            float push = s_push;
            float ppu = push * su + (1.f - push) * p2;
            s_w[lane] = ppu;
            s_ptr[lane] = (push > cTH) ? ppu : p2;
        }
        __syncthreads();

        // ---- P5: content update (local: s_w, s_pushv) ----
        if (s_push > cTH) {
            #pragma unroll
            for (int it = 0; it < 16; ++it) {
                int idx = tid + it * 256;
                int k = idx >> 6, d = idx & 63;
                float w = s_w[k];
                s_content[k][d] = s_content[k][d] * (1.f - w) + s_pushv[d] * w;
            }
        }
        __syncthreads();
    }
}

// =================== Binning: group (b,t) tasks by symbol ===================
__global__ void k_count(const int* __restrict__ seq, int* __restrict__ counts) {
    int i = blockIdx.x * 256 + threadIdx.x;
    if (i < NTASK) atomicAdd(&counts[seq[i]], 1);
}
__global__ void k_scan(const int* __restrict__ counts, int* __restrict__ offsets,
                       int* __restrict__ cursor) {
    const int lane = threadIdx.x & 63;
    int c0 = counts[lane], c1 = counts[64 + lane];
    int s0 = c0, s1 = c1;
    #pragma unroll
    for (int m = 1; m < 64; m <<= 1) {
        int t0 = __shfl_up(s0, m);
        int t1 = __shfl_up(s1, m);
        if (lane >= m) { s0 += t0; s1 += t1; }
    }
    int tot0 = __shfl(s0, 63);
    int e0 = s0 - c0;
    int e1 = tot0 + s1 - c1;
    offsets[lane] = e0;       cursor[lane] = e0;
    offsets[64 + lane] = e1;  cursor[64 + lane] = e1;
    if (lane == 63) offsets[128] = tot0 + __shfl(s1, 63);
}
__global__ void k_scatter(const int* __restrict__ seq, int* __restrict__ cursor,
                          int* __restrict__ tasks) {
    int i = blockIdx.x * 256 + threadIdx.x;
    if (i < NTASK) {
        int pos = atomicAdd(&cursor[seq[i]], 1);
        tasks[pos] = i;
    }
}

// ====== Phase 2: output head. LDS-staged O rows, NT loads, 8 tasks/wave ======
__global__ __launch_bounds__(512, 2)
void p2_kernel(const float* __restrict__ Om,      // (S,I,D,NO)
               const float* __restrict__ stbuf,   // (B*T,128)
               const int* __restrict__ offsets,   // (129,)
               const int* __restrict__ tasks,     // (B*T,)
               float* __restrict__ out)           // (B*T,NO)
{
    const int g = blockIdx.x >> 1, h = blockIdx.x & 1;
    const int tid = threadIdx.x, wave = tid >> 6, lane = tid & 63;
    const int dq = lane >> 4, o4 = lane & 15;

    const int beg = offsets[g], end = offsets[g + 1];
    const int n = end - beg, half = (n + 1) >> 1;
    const int hbeg = beg + h * half;
    const int hend = h ? end : (beg + half);
    const int cnt = hend - hbeg;
    if (cnt <= 0) return;
    const int nsweep = (cnt + 63) >> 6;

    __shared__ vf4 sO[2][1024];

    const vf4* O0 = reinterpret_cast<const vf4*>(Om) + (size_t)g * 1024;
    const size_t rowstride = (size_t)cI * 1024;

    for (int sweep = 0; sweep < nsweep; ++sweep) {
        int   tsk[8];
        bool  val[8];
        float stv[8][16];
        float sstate[8];
        vf4   acc[8];
        #pragma unroll
        for (int u = 0; u < 8; ++u) {
            int idx = hbeg + sweep * 64 + (u >> 2) * 32 + wave * 4 + (u & 3);
            bool v = idx < hend;
            val[u] = v;
            int id = tasks[v ? idx : hbeg];
            id = __builtin_amdgcn_readfirstlane(id);
            tsk[u] = id;
            const float* sp = stbuf + (size_t)id * 128;
            #pragma unroll
            for (int i = 0; i < 16; ++i) stv[u][i] = sp[dq * 16 + i];
            sstate[u] = sp[64 + lane];
            acc[u].x = 0.f; acc[u].y = 0.f; acc[u].z = 0.f; acc[u].w = 0.f;
        }

        vf4 r0 = __builtin_nontemporal_load(O0 + (size_t)tid * 2);
        vf4 r1 = __builtin_nontemporal_load(O0 + (size_t)tid * 2 + 1);

        for (int s = 0; s < cS; ++s) {
            sO[s & 1][tid * 2]     = r0;
            sO[s & 1][tid * 2 + 1] = r1;
            __syncthreads();
            if (s + 1 < cS) {
                const vf4* nr = O0 + (size_t)(s + 1) * rowstride;
                r0 = __builtin_nontemporal_load(nr + (size_t)tid * 2);
                r1 = __builtin_nontemporal_load(nr + (size_t)tid * 2 + 1);
            }
            vf4 part[8];
            #pragma unroll
            for (int u = 0; u < 8; ++u) { part[u].x = 0.f; part[u].y = 0.f; part[u].z = 0.f; part[u].w = 0.f; }
            #pragma unroll
            for (int i = 0; i < 16; ++i) {
                vf4 ovi = sO[s & 1][(dq * 16 + i) * 16 + o4];
                #pragma unroll
                for (int u = 0; u < 8; ++u) {
                    float x = stv[u][i];
                    part[u].x = fmaf(x, ovi.x, part[u].x);
                    part[u].y = fmaf(x, ovi.y, part[u].y);
                    part[u].z = fmaf(x, ovi.z, part[u].z);
                    part[u].w = fmaf(x, ovi.w, part[u].w);
                }
            }
            #pragma unroll
            for (int u = 0; u < 8; ++u) {
                vf4 a = part[u];
                #pragma unroll
                for (int m = 16; m < 64; m <<= 1) {
                    a.x += __shfl_xor(a.x, m); a.y += __shfl_xor(a.y, m);
                    a.z += __shfl_xor(a.z, m); a.w += __shfl_xor(a.w, m);
                }
                float mx = fmaxf(fmaxf(a.x, a.y), fmaxf(a.z, a.w));
                #pragma unroll
                for (int m = 1; m < 16; m <<= 1) mx = fmaxf(mx, __shfl_xor(mx, m));
                vf4 e;
                e.x = expf(a.x - mx); e.y = expf(a.y - mx);
                e.z = expf(a.z - mx); e.w = expf(a.w - mx);
                float sm = e.x + e.y + e.z + e.w;
                #pragma unroll
                for (int m = 1; m < 16; m <<= 1) sm += __shfl_xor(sm, m);
                float coef = __shfl(sstate[u], s) / sm;
                acc[u].x = fmaf(coef, e.x, acc[u].x);
                acc[u].y = fmaf(coef, e.y, acc[u].y);
                acc[u].z = fmaf(coef, e.z, acc[u].z);
                acc[u].w = fmaf(coef, e.w, acc[u].w);
            }
        }
        #pragma unroll
        for (int u = 0; u < 8; ++u) {
            if (val[u] && dq == 0) {
                float* op = out + (size_t)tsk[u] * cNO + o4 * 4;
                op[0] = acc[u].x; op[1] = acc[u].y; op[2] = acc[u].z; op[3] = acc[u].w;
            }
        }
    }
}

// =================== Fallback: monolithic (if ws too small) ===================
__global__ __launch_bounds__(512, 1)
void fpt_mono(const int* __restrict__ seq, const float* __restrict__ Tm,
              const float* __restrict__ Om, const float* __restrict__ pgate,
              const float* __restrict__ qgate, const float* __restrict__ pval,
              const float* __restrict__ initl, float* __restrict__ out)
{
    const int b = blockIdx.x;
    const int tid = threadIdx.x;
    const int wave = tid >> 6, lane = tid & 63;
    const int dq = lane >> 4, o4 = lane & 15;

    __shared__ float s_state[cS], s_nstate[cS], s_stack[cD], s_pushv[cD];
    __shared__ float s_ptr[cK], s_ptr2[cK], s_w[cK];
    __shared__ float s_content[cK][cD];
    __shared__ float s_redA[8][64], s_redB[8][64];
    __shared__ float s_opart[4][cNO], s_npart[4][cS];
    __shared__ float s_push, s_pop;

    if (wave == 0) {
        float v = initl[lane];
        float m = v;
        #pragma unroll
        for (int sh = 1; sh < 64; sh <<= 1) m = fmaxf(m, __shfl_xor(m, sh));
        float e = expf(v - m);
        float s = e;
        #pragma unroll
        for (int sh = 1; sh < 64; sh <<= 1) s += __shfl_xor(s, sh);
        s_state[lane] = e / s;
    } else if (wave == 1) s_ptr[lane] = (lane == 0) ? 1.0f : 0.0f;
    for (int idx = tid; idx < cK * cD; idx += 512) (&s_content[0][0])[idx] = 0.0f;
    __syncthreads();

    for (int t = 0; t < cT; ++t) {
        const int inp = seq[b * cT + t];
        {
            float accA = 0.f, accB = 0.f;
            #pragma unroll
            for (int j = 0; j < 8; ++j) {
                int k = wave * 8 + j;
                accA += s_ptr[k] * s_content[k][lane];
                accB += s_state[k] * pval[(k * cI + inp) * cD + lane];
            }
            s_redA[wave][lane] = accA;
            s_redB[wave][lane] = accB;
        }
        __syncthreads();
        if (wave == 0) {
            float a = 0.f;
            #pragma unroll
            for (int g = 0; g < 8; ++g) a += s_redA[g][lane];
            s_stack[lane] = a;
        } else if (wave == 1) {
            float a = 0.f;
            #pragma unroll
            for (int g = 0; g < 8; ++g) a += s_redB[g][lane];
            s_pushv[lane] = tanhf(a);
        } else if (wave == 2) {
            float v = pgate[lane * cI + inp] * s_state[lane];
            #pragma unroll
            for (int sh = 1; sh < 64; sh <<= 1) v += __shfl_xor(v, sh);
            if (lane == 0) s_push = 1.0f / (1.0f + expf(-v));
        } else if (wave == 3) {
            float v = qgate[lane * cI + inp] * s_state[lane];
            #pragma unroll
            for (int sh = 1; sh < 64; sh <<= 1) v += __shfl_xor(v, sh);
            if (lane == 0) s_pop = 1.0f / (1.0f + expf(-v));
        }
        __syncthreads();
        {
            const bool isO = (wave < 4);
            const int w4 = wave & 3;
            const float* Mbase = isO ? Om : Tm;
            float xs[16];
            #pragma unroll
            for (int i = 0; i < 16; ++i) xs[i] = s_stack[dq * 16 + i];
            float4 oacc = make_float4(0.f, 0.f, 0.f, 0.f);
            for (int r = 0; r < 16; ++r) {
                const int s = w4 * 16 + r;
                const float4* rowp =
                    reinterpret_cast<const float4*>(Mbase + (size_t)(s * cI + inp) * (cD * 64)) + o4;
                float4 acc = make_float4(0.f, 0.f, 0.f, 0.f);
                #pragma unroll
                for (int i = 0; i < 16; ++i) {
                    float4 mv = rowp[(dq * 16 + i) * 16];
                    float xd = xs[i];
                    acc.x = fmaf(xd, mv.x, acc.x); acc.y = fmaf(xd, mv.y, acc.y);
                    acc.z = fmaf(xd, mv.z, acc.z); acc.w = fmaf(xd, mv.w, acc.w);
                }
                #pragma unroll
                for (int m = 16; m < 64; m <<= 1) {
                    acc.x += __shfl_xor(acc.x, m); acc.y += __shfl_xor(acc.y, m);
                    acc.z += __shfl_xor(acc.z, m); acc.w += __shfl_xor(acc.w, m);
                }
                float mx = fmaxf(fmaxf(acc.x, acc.y), fmaxf(acc.z, acc.w));
                #pragma unroll
                for (int m = 1; m < 16; m <<= 1) mx = fmaxf(mx, __shfl_xor(mx, m));
                float4 e;
                e.x = expf(acc.x - mx); e.y = expf(acc.y - mx);
                e.z = expf(acc.z - mx); e.w = expf(acc.w - mx);
                float sm = e.x + e.y + e.z + e.w;
                #pragma unroll
                for (int m = 1; m < 16; m <<= 1) sm += __shfl_xor(sm, m);
                float coef = s_state[s] / sm;
                oacc.x = fmaf(coef, e.x, oacc.x); oacc.y = fmaf(coef, e.y, oacc.y);
                oacc.z = fmaf(coef, e.z, oacc.z); oacc.w = fmaf(coef, e.w, oacc.w);
            }
            if (dq == 0) {
                float* dst = isO ? &s_opart[w4][0] : &s_npart[w4][0];
                dst[o4 * 4 + 0] = oacc.x; dst[o4 * 4 + 1] = oacc.y;
                dst[o4 * 4 + 2] = oacc.z; dst[o4 * 4 + 3] = oacc.w;
            }
        }
        __syncthreads();
        if (wave == 0) {
            float o = s_opart[0][lane] + s_opart[1][lane] + s_opart[2][lane] + s_opart[3][lane];
            out[((size_t)b * cT + t) * cNO + lane] = o;
        } else if (wave == 1) {
            s_nstate[lane] = s_npart[0][lane] + s_npart[1][lane] + s_npart[2][lane] + s_npart[3][lane];
        } else if (wave == 2) {
            float p = s_ptr[lane];
            float sd = (lane < cK - 1) ? s_ptr[lane + 1] : 0.f;
            float pop = s_pop;
            float pp = pop * sd + (1.f - pop) * p;
            s_ptr2[lane] = (pop > cTH) ? pp : p;
        }
        __syncthreads();
        if (wave == 0) {
            float p2 = s_ptr2[lane];
            float su = (lane > 0) ? s_ptr2[lane - 1] : 0.f;
            float push = s_push;
            float pp = push * su + (1.f - push) * p2;
            s_w[lane] = pp;
            s_ptr[lane] = (push > cTH) ? pp : p2;
        } else if (wave == 1) {
            s_state[lane] = s_nstate[lane];
        }
        __syncthreads();
        if (s_push > cTH) {
            for (int idx = tid; idx < cK * cD; idx += 512) {
                int k = idx >> 6, d = idx & 63;
                float w = s_w[k];
                s_content[k][d] = s_content[k][d] * (1.f - w) + s_pushv[d] * w;
            }
        }
        __syncthreads();
    }
}
} // namespace

extern "C" void kernel_launch(void* const* d_in, const int* in_sizes, int n_in,
                              void* d_out, int out_size, void* d_ws, size_t ws_size,
                              hipStream_t stream) {
    const int*   seq = (const int*)d_in[0];
    const float* Tm  = (const float*)d_in[1];
    const float* Om  = (const float*)d_in[2];
    const float* pg  = (const float*)d_in[3];
    const float* qg  = (const float*)d_in[4];
    const float* pv  = (const float*)d_in[5];
    const float* il  = (const float*)d_in[6];
    float* o = (float*)d_out;

    const size_t stbuf_bytes  = (size_t)NTASK * 128 * sizeof(float);   // 8 MB
    const size_t counts_off   = stbuf_bytes;
    const size_t offsets_off  = counts_off + 128 * sizeof(int);
    const size_t cursor_off   = offsets_off + 132 * sizeof(int);
    const size_t tasks_off    = cursor_off + 128 * sizeof(int);
    const size_t cnt_off      = tasks_off + (size_t)NTASK * sizeof(int);
    const size_t gpart_off    = cnt_off + (size_t)NTASK * sizeof(int);
    const size_t need         = gpart_off + (size_t)cB * 2 * NSPLIT * 64 * sizeof(float);

    if (ws_size < need) {
        hipLaunchKernelGGL(fpt_mono, dim3(cB), dim3(512), 0, stream,
                           seq, Tm, Om, pg, qg, pv, il, o);
        return;
    }

    float* stbuf  = (float*)d_ws;
    int* counts   = (int*)((char*)d_ws + counts_off);
    int* offsets  = (int*)((char*)d_ws + offsets_off);
    int* cursor   = (int*)((char*)d_ws + cursor_off);
    int* tasks    = (int*)((char*)d_ws + tasks_off);
    int* cnt      = (int*)((char*)d_ws + cnt_off);
    float* gpart  = (float*)((char*)d_ws + gpart_off);

    hipMemsetAsync(counts, 0, 128 * sizeof(int), stream);
    hipMemsetAsync(cnt, 0, (size_t)NTASK * sizeof(int), stream);
    hipLaunchKernelGGL(k_count,   dim3(NTASK / 256), dim3(256), 0, stream, seq, counts);
    hipLaunchKernelGGL(k_scan,    dim3(1),           dim3(64),  0, stream, counts, offsets, cursor);
    hipLaunchKernelGGL(k_scatter, dim3(NTASK / 256), dim3(256), 0, stream, seq, cursor, tasks);
    hipLaunchKernelGGL(p1_kernel, dim3(cB * NSPLIT), dim3(256), 0, stream,
                       seq, Tm, pg, qg, pv, il, stbuf, cnt, gpart);
    hipLaunchKernelGGL(p2_kernel, dim3(256), dim3(512), 0, stream, Om, stbuf, offsets, tasks, o);
}

// Round 14
// 2779.650 us; speedup vs baseline: 1.2745x; 1.0074x over previous
//
#include <hip/hip_runtime.h>
#include <math.h>

namespace {
constexpr int cS = 64, cI = 128, cNO = 64, cK = 64, cD = 64, cB = 64, cT = 256;
constexpr float cTH = 0.01f;
constexpr int NTASK = cB * cT;
constexpr int NSPLIT = 8;                  // WGs per sequence (R11 optimum)
typedef float vf4 __attribute__((ext_vector_type(4)));

__device__ inline void st_agent(float* p, float v) {
    __hip_atomic_store(p, v, __ATOMIC_RELAXED, __HIP_MEMORY_SCOPE_AGENT);
}
__device__ inline float ld_agent(const float* p) {
    return __hip_atomic_load(p, __ATOMIC_RELAXED, __HIP_MEMORY_SCOPE_AGENT);
}

// ====== Phase 1: recurrence, 8 WGs/seq x 256 thr, 2 WGs/CU (R11 structure,
//        minus one barrier: stack_top computed fully per-wave, in R11's exact
//        4x16 grouped summation order => bit-identical results) ======
__global__ __launch_bounds__(256, 2)
void p1_kernel(const int* __restrict__ seq,
               const float* __restrict__ Tm,     // (S,I,D,S)
               const float* __restrict__ pgate,  // (S,I,1)
               const float* __restrict__ qgate,  // (S,I,1)
               const float* __restrict__ pval,   // (S,I,D)
               const float* __restrict__ initl,  // (S,)
               float* __restrict__ stbuf,        // (B*T,128)
               int* __restrict__ cnt,            // (B*T) zeroed per launch
               float* __restrict__ gpart)        // (B,2,8,128)
{
    const int b  = blockIdx.x >> 3;
    const int jw = blockIdx.x & 7;
    const int tid = threadIdx.x;
    const int wave = tid >> 6, lane = tid & 63;
    const int dq = lane >> 4, o4 = lane & 15;

    __shared__ float s_state[cS], s_pushv[cD];
    __shared__ float s_ptr[cK], s_w[cK];
    __shared__ float s_content[cK][cD];
    __shared__ float s_redB[4][64], s_npart[4][64];
    __shared__ int   s_seq[cT];
    __shared__ float s_push, s_pop;

    if (wave == 0) {
        float v = initl[lane];
        float m = v;
        #pragma unroll
        for (int sh = 1; sh < 64; sh <<= 1) m = fmaxf(m, __shfl_xor(m, sh));
        float e = expf(v - m);
        float s = e;
        #pragma unroll
        for (int sh = 1; sh < 64; sh <<= 1) s += __shfl_xor(s, sh);
        s_state[lane] = e / s;
    } else if (wave == 1) {
        s_ptr[lane] = (lane == 0) ? 1.0f : 0.0f;
    }
    for (int i = tid; i < cK * cD; i += 256) (&s_content[0][0])[i] = 0.f;
    s_seq[tid] = seq[b * cT + tid];
    __syncthreads();

    for (int t = 0; t < cT; ++t) {
        const int inp = s_seq[t];

        // ---- A: every wave computes FULL stack_top (R11's 4x16 grouped order);
        //         per-wave pv partials; gates; stbuf publish ----
        float st;
        {
            float g0 = 0.f, g1 = 0.f, g2 = 0.f, g3 = 0.f;
            #pragma unroll
            for (int j = 0; j < 16; ++j) g0 += s_ptr[j]      * s_content[j][lane];
            #pragma unroll
            for (int j = 0; j < 16; ++j) g1 += s_ptr[16 + j] * s_content[16 + j][lane];
            #pragma unroll
            for (int j = 0; j < 16; ++j) g2 += s_ptr[32 + j] * s_content[32 + j][lane];
            #pragma unroll
            for (int j = 0; j < 16; ++j) g3 += s_ptr[48 + j] * s_content[48 + j][lane];
            st = ((g0 + g1) + g2) + g3;
        }
        {
            float accB = 0.f;
            #pragma unroll
            for (int j = 0; j < 2; ++j) {
                int k = jw * 8 + wave * 2 + j;
                accB += s_state[k] * pval[((size_t)k * cI + inp) * cD + lane];
            }
            s_redB[wave][lane] = accB;
        }
        if (wave == 2) {
            float v = pgate[lane * cI + inp] * s_state[lane];
            #pragma unroll
            for (int sh = 1; sh < 64; sh <<= 1) v += __shfl_xor(v, sh);
            if (lane == 0) s_push = 1.0f / (1.0f + expf(-v));
        } else if (wave == 3) {
            float v = qgate[lane * cI + inp] * s_state[lane];
            #pragma unroll
            for (int sh = 1; sh < 64; sh <<= 1) v += __shfl_xor(v, sh);
            if (lane == 0) s_pop = 1.0f / (1.0f + expf(-v));
        }
        float* sb = stbuf + (size_t)(b * cT + t) * 128;
        if (jw == 0 && wave == 0) { sb[lane] = st; sb[64 + lane] = s_state[lane]; }
        __syncthreads();

        // ---- B: this wave's 2 T-rows (xs via in-wave shuffles of st) ----
        {
            float xs[16];
            #pragma unroll
            for (int i = 0; i < 16; ++i) xs[i] = __shfl(st, dq * 16 + i);

            const int sA = jw * 8 + wave * 2;
            const int sB = sA + 1;
            const vf4* rpA = reinterpret_cast<const vf4*>(
                Tm + (size_t)(sA * cI + inp) * (cD * cS)) + o4;
            const vf4* rpB = reinterpret_cast<const vf4*>(
                Tm + (size_t)(sB * cI + inp) * (cD * cS)) + o4;
            vf4 va[16], vb[16];
            #pragma unroll
            for (int i = 0; i < 16; ++i) {
                va[i] = rpA[(dq * 16 + i) * 16];
                vb[i] = rpB[(dq * 16 + i) * 16];
            }
            vf4 aA, aB;
            aA.x = 0.f; aA.y = 0.f; aA.z = 0.f; aA.w = 0.f;
            aB.x = 0.f; aB.y = 0.f; aB.z = 0.f; aB.w = 0.f;
            #pragma unroll
            for (int i = 0; i < 16; ++i) {
                float x = xs[i];
                aA.x = fmaf(x, va[i].x, aA.x); aA.y = fmaf(x, va[i].y, aA.y);
                aA.z = fmaf(x, va[i].z, aA.z); aA.w = fmaf(x, va[i].w, aA.w);
                aB.x = fmaf(x, vb[i].x, aB.x); aB.y = fmaf(x, vb[i].y, aB.y);
                aB.z = fmaf(x, vb[i].z, aB.z); aB.w = fmaf(x, vb[i].w, aB.w);
            }
            #pragma unroll
            for (int m = 16; m < 64; m <<= 1) {
                aA.x += __shfl_xor(aA.x, m); aA.y += __shfl_xor(aA.y, m);
                aA.z += __shfl_xor(aA.z, m); aA.w += __shfl_xor(aA.w, m);
                aB.x += __shfl_xor(aB.x, m); aB.y += __shfl_xor(aB.y, m);
                aB.z += __shfl_xor(aB.z, m); aB.w += __shfl_xor(aB.w, m);
            }
            float mA = fmaxf(fmaxf(aA.x, aA.y), fmaxf(aA.z, aA.w));
            float mB = fmaxf(fmaxf(aB.x, aB.y), fmaxf(aB.z, aB.w));
            #pragma unroll
            for (int m = 1; m < 16; m <<= 1) {
                mA = fmaxf(mA, __shfl_xor(mA, m));
                mB = fmaxf(mB, __shfl_xor(mB, m));
            }
            vf4 eA, eB;
            eA.x = expf(aA.x - mA); eA.y = expf(aA.y - mA);
            eA.z = expf(aA.z - mA); eA.w = expf(aA.w - mA);
            eB.x = expf(aB.x - mB); eB.y = expf(aB.y - mB);
            eB.z = expf(aB.z - mB); eB.w = expf(aB.w - mB);
            float smA = eA.x + eA.y + eA.z + eA.w;
            float smB = eB.x + eB.y + eB.z + eB.w;
            #pragma unroll
            for (int m = 1; m < 16; m <<= 1) {
                smA += __shfl_xor(smA, m);
                smB += __shfl_xor(smB, m);
            }
            float cA = s_state[sA] / smA;
            float cB = s_state[sB] / smB;
            vf4 nacc;
            nacc.x = cA * eA.x + cB * eB.x;
            nacc.y = cA * eA.y + cB * eB.y;
            nacc.z = cA * eA.z + cB * eB.z;
            nacc.w = cA * eA.w + cB * eB.w;
            if (dq == 0) {
                s_npart[wave][o4 * 4 + 0] = nacc.x;
                s_npart[wave][o4 * 4 + 1] = nacc.y;
                s_npart[wave][o4 * 4 + 2] = nacc.z;
                s_npart[wave][o4 * 4 + 3] = nacc.w;
            }
        }
        __syncthreads();

        // ---- C: wave0 = publish/flag/poll/combine; wave1 = pointer pop+push ----
        if (wave == 0) {
            float* gq = gpart + ((size_t)(b * 2 + (t & 1)) * NSPLIT + jw) * 128;
            float np  = s_npart[0][lane] + s_npart[1][lane] + s_npart[2][lane] + s_npart[3][lane];
            float pvp = s_redB[0][lane] + s_redB[1][lane] + s_redB[2][lane] + s_redB[3][lane];
            st_agent(gq + lane, np);
            st_agent(gq + 64 + lane, pvp);
            asm volatile("s_waitcnt vmcnt(0)" ::: "memory");
            int* c = cnt + b * cT + t;
            if (lane == 0)
                __hip_atomic_fetch_add(c, 1, __ATOMIC_RELAXED, __HIP_MEMORY_SCOPE_AGENT);
            while (__hip_atomic_load(c, __ATOMIC_RELAXED, __HIP_MEMORY_SCOPE_AGENT) < NSPLIT) {}
            const float* gb = gpart + (size_t)(b * 2 + (t & 1)) * NSPLIT * 128;
            float ns = 0.f, pvs = 0.f;
            #pragma unroll
            for (int q = 0; q < NSPLIT; ++q) {
                ns  += ld_agent(gb + q * 128 + lane);
                pvs += ld_agent(gb + q * 128 + 64 + lane);
            }
            s_state[lane] = ns;
            s_pushv[lane] = tanhf(pvs);
        } else if (wave == 1) {
            float p  = s_ptr[lane];
            float sd = (lane < cK - 1) ? s_ptr[lane + 1] : 0.f;
            float pop = s_pop;
            float ppo = pop * sd + (1.f - pop) * p;
            float p2  = (pop > cTH) ? ppo : p;
            float su  = __shfl_up(p2, 1);
            if (lane == 0) su = 0.f;
            float push = s_push;
            float ppu = push * su + (1.f - push) * p2;
            s_w[lane] = ppu;
            s_ptr[lane] = (push > cTH) ? ppu : p2;
        }
        __syncthreads();

        // ---- C3: content update (uniform branch, identical across WGs) ----
        if (s_push > cTH) {
            #pragma unroll
            for (int it = 0; it < 16; ++it) {
                int idx = tid + it * 256;
                int k = idx >> 6, d = idx & 63;
                float w = s_w[k];
                s_content[k][d] = s_content[k][d] * (1.f - w) + s_pushv[d] * w;
            }
        }
        __syncthreads();
    }
}

// =================== Binning: group (b,t) tasks by symbol ===================
__global__ void k_count(const int* __restrict__ seq, int* __restrict__ counts) {
    int i = blockIdx.x * 256 + threadIdx.x;
    if (i < NTASK) atomicAdd(&counts[seq[i]], 1);
}
__global__ void k_scan(const int* __restrict__ counts, int* __restrict__ offsets,
                       int* __restrict__ cursor) {
    const int lane = threadIdx.x & 63;
    int c0 = counts[lane], c1 = counts[64 + lane];
    int s0 = c0, s1 = c1;
    #pragma unroll
    for (int m = 1; m < 64; m <<= 1) {
        int t0 = __shfl_up(s0, m);
        int t1 = __shfl_up(s1, m);
        if (lane >= m) { s0 += t0; s1 += t1; }
    }
    int tot0 = __shfl(s0, 63);
    int e0 = s0 - c0;
    int e1 = tot0 + s1 - c1;
    offsets[lane] = e0;       cursor[lane] = e0;
    offsets[64 + lane] = e1;  cursor[64 + lane] = e1;
    if (lane == 63) offsets[128] = tot0 + __shfl(s1, 63);
}
__global__ void k_scatter(const int* __restrict__ seq, int* __restrict__ cursor,
                          int* __restrict__ tasks) {
    int i = blockIdx.x * 256 + threadIdx.x;
    if (i < NTASK) {
        int pos = atomicAdd(&cursor[seq[i]], 1);
        tasks[pos] = i;
    }
}

// ====== Phase 2: output head. LDS-staged O rows, NT loads, 8 tasks/wave ======
__global__ __launch_bounds__(512, 2)
void p2_kernel(const float* __restrict__ Om,      // (S,I,D,NO)
               const float* __restrict__ stbuf,   // (B*T,128)
               const int* __restrict__ offsets,   // (129,)
               const int* __restrict__ tasks,     // (B*T,)
               float* __restrict__ out)           // (B*T,NO)
{
    const int g = blockIdx.x >> 1, h = blockIdx.x & 1;
    const int tid = threadIdx.x, wave = tid >> 6, lane = tid & 63;
    const int dq = lane >> 4, o4 = lane & 15;

    const int beg = offsets[g], end = offsets[g + 1];
    const int n = end - beg, half = (n + 1) >> 1;
    const int hbeg = beg + h * half;
    const int hend = h ? end : (beg + half);
    const int cnt = hend - hbeg;
    if (cnt <= 0) return;
    const int nsweep = (cnt + 63) >> 6;

    __shared__ vf4 sO[2][1024];

    const vf4* O0 = reinterpret_cast<const vf4*>(Om) + (size_t)g * 1024;
    const size_t rowstride = (size_t)cI * 1024;

    for (int sweep = 0; sweep < nsweep; ++sweep) {
        int   tsk[8];
        bool  val[8];
        float stv[8][16];
        float sstate[8];
        vf4   acc[8];
        #pragma unroll
        for (int u = 0; u < 8; ++u) {
            int idx = hbeg + sweep * 64 + (u >> 2) * 32 + wave * 4 + (u & 3);
            bool v = idx < hend;
            val[u] = v;
            int id = tasks[v ? idx : hbeg];
            id = __builtin_amdgcn_readfirstlane(id);
            tsk[u] = id;
            const float* sp = stbuf + (size_t)id * 128;
            #pragma unroll
            for (int i = 0; i < 16; ++i) stv[u][i] = sp[dq * 16 + i];
            sstate[u] = sp[64 + lane];
            acc[u].x = 0.f; acc[u].y = 0.f; acc[u].z = 0.f; acc[u].w = 0.f;
        }

        vf4 r0 = __builtin_nontemporal_load(O0 + (size_t)tid * 2);
        vf4 r1 = __builtin_nontemporal_load(O0 + (size_t)tid * 2 + 1);

        for (int s = 0; s < cS; ++s) {
            sO[s & 1][tid * 2]     = r0;
            sO[s & 1][tid * 2 + 1] = r1;
            __syncthreads();
            if (s + 1 < cS) {
                const vf4* nr = O0 + (size_t)(s + 1) * rowstride;
                r0 = __builtin_nontemporal_load(nr + (size_t)tid * 2);
                r1 = __builtin_nontemporal_load(nr + (size_t)tid * 2 + 1);
            }
            vf4 part[8];
            #pragma unroll
            for (int u = 0; u < 8; ++u) { part[u].x = 0.f; part[u].y = 0.f; part[u].z = 0.f; part[u].w = 0.f; }
            #pragma unroll
            for (int i = 0; i < 16; ++i) {
                vf4 ovi = sO[s & 1][(dq * 16 + i) * 16 + o4];
                #pragma unroll
                for (int u = 0; u < 8; ++u) {
                    float x = stv[u][i];
                    part[u].x = fmaf(x, ovi.x, part[u].x);
                    part[u].y = fmaf(x, ovi.y, part[u].y);
                    part[u].z = fmaf(x, ovi.z, part[u].z);
                    part[u].w = fmaf(x, ovi.w, part[u].w);
                }
            }
            #pragma unroll
            for (int u = 0; u < 8; ++u) {
                vf4 a = part[u];
                #pragma unroll
                for (int m = 16; m < 64; m <<= 1) {
                    a.x += __shfl_xor(a.x, m); a.y += __shfl_xor(a.y, m);
                    a.z += __shfl_xor(a.z, m); a.w += __shfl_xor(a.w, m);
                }
                float mx = fmaxf(fmaxf(a.x, a.y), fmaxf(a.z, a.w));
                #pragma unroll
                for (int m = 1; m < 16; m <<= 1) mx = fmaxf(mx, __shfl_xor(mx, m));
                vf4 e;
                e.x = expf(a.x - mx); e.y = expf(a.y - mx);
                e.z = expf(a.z - mx); e.w = expf(a.w - mx);
                float sm = e.x + e.y + e.z + e.w;
                #pragma unroll
                for (int m = 1; m < 16; m <<= 1) sm += __shfl_xor(sm, m);
                float coef = __shfl(sstate[u], s) / sm;
                acc[u].x = fmaf(coef, e.x, acc[u].x);
                acc[u].y = fmaf(coef, e.y, acc[u].y);
                acc[u].z = fmaf(coef, e.z, acc[u].z);
                acc[u].w = fmaf(coef, e.w, acc[u].w);
            }
        }
        #pragma unroll
        for (int u = 0; u < 8; ++u) {
            if (val[u] && dq == 0) {
                float* op = out + (size_t)tsk[u] * cNO + o4 * 4;
                op[0] = acc[u].x; op[1] = acc[u].y; op[2] = acc[u].z; op[3] = acc[u].w;
            }
        }
    }
}

// =================== Fallback: monolithic (if ws too small) ===================
__global__ __launch_bounds__(512, 1)
void fpt_mono(const int* __restrict__ seq, const float* __restrict__ Tm,
              const float* __restrict__ Om, const float* __restrict__ pgate,
              const float* __restrict__ qgate, const float* __restrict__ pval,
              const float* __restrict__ initl, float* __restrict__ out)
{
    const int b = blockIdx.x;
    const int tid = threadIdx.x;
    const int wave = tid >> 6, lane = tid & 63;
    const int dq = lane >> 4, o4 = lane & 15;

    __shared__ float s_state[cS], s_nstate[cS], s_stack[cD], s_pushv[cD];
    __shared__ float s_ptr[cK], s_ptr2[cK], s_w[cK];
    __shared__ float s_content[cK][cD];
    __shared__ float s_redA[8][64], s_redB[8][64];
    __shared__ float s_opart[4][cNO], s_npart[4][cS];
    __shared__ float s_push, s_pop;

    if (wave == 0) {
        float v = initl[lane];
        float m = v;
        #pragma unroll
        for (int sh = 1; sh < 64; sh <<= 1) m = fmaxf(m, __shfl_xor(m, sh));
        float e = expf(v - m);
        float s = e;
        #pragma unroll
        for (int sh = 1; sh < 64; sh <<= 1) s += __shfl_xor(s, sh);
        s_state[lane] = e / s;
    } else if (wave == 1) s_ptr[lane] = (lane == 0) ? 1.0f : 0.0f;
    for (int idx = tid; idx < cK * cD; idx += 512) (&s_content[0][0])[idx] = 0.0f;
    __syncthreads();

    for (int t = 0; t < cT; ++t) {
        const int inp = seq[b * cT + t];
        {
            float accA = 0.f, accB = 0.f;
            #pragma unroll
            for (int j = 0; j < 8; ++j) {
                int k = wave * 8 + j;
                accA += s_ptr[k] * s_content[k][lane];
                accB += s_state[k] * pval[(k * cI + inp) * cD + lane];
            }
            s_redA[wave][lane] = accA;
            s_redB[wave][lane] = accB;
        }
        __syncthreads();
        if (wave == 0) {
            float a = 0.f;
            #pragma unroll
            for (int g = 0; g < 8; ++g) a += s_redA[g][lane];
            s_stack[lane] = a;
        } else if (wave == 1) {
            float a = 0.f;
            #pragma unroll
            for (int g = 0; g < 8; ++g) a += s_redB[g][lane];
            s_pushv[lane] = tanhf(a);
        } else if (wave == 2) {
            float v = pgate[lane * cI + inp] * s_state[lane];
            #pragma unroll
            for (int sh = 1; sh < 64; sh <<= 1) v += __shfl_xor(v, sh);
            if (lane == 0) s_push = 1.0f / (1.0f + expf(-v));
        } else if (wave == 3) {
            float v = qgate[lane * cI + inp] * s_state[lane];
            #pragma unroll
            for (int sh = 1; sh < 64; sh <<= 1) v += __shfl_xor(v, sh);
            if (lane == 0) s_pop = 1.0f / (1.0f + expf(-v));
        }
        __syncthreads();
        {
            const bool isO = (wave < 4);
            const int w4 = wave & 3;
            const float* Mbase = isO ? Om : Tm;
            float xs[16];
            #pragma unroll
            for (int i = 0; i < 16; ++i) xs[i] = s_stack[dq * 16 + i];
            float4 oacc = make_float4(0.f, 0.f, 0.f, 0.f);
            for (int r = 0; r < 16; ++r) {
                const int s = w4 * 16 + r;
                const float4* rowp =
                    reinterpret_cast<const float4*>(Mbase + (size_t)(s * cI + inp) * (cD * 64)) + o4;
                float4 acc = make_float4(0.f, 0.f, 0.f, 0.f);
                #pragma unroll
                for (int i = 0; i < 16; ++i) {
                    float4 mv = rowp[(dq * 16 + i) * 16];
                    float xd = xs[i];
                    acc.x = fmaf(xd, mv.x, acc.x); acc.y = fmaf(xd, mv.y, acc.y);
                    acc.z = fmaf(xd, mv.z, acc.z); acc.w = fmaf(xd, mv.w, acc.w);
                }
                #pragma unroll
                for (int m = 16; m < 64; m <<= 1) {
                    acc.x += __shfl_xor(acc.x, m); acc.y += __shfl_xor(acc.y, m);
                    acc.z += __shfl_xor(acc.z, m); acc.w += __shfl_xor(acc.w, m);
                }
                float mx = fmaxf(fmaxf(acc.x, acc.y), fmaxf(acc.z, acc.w));
                #pragma unroll
                for (int m = 1; m < 16; m <<= 1) mx = fmaxf(mx, __shfl_xor(mx, m));
                float4 e;
                e.x = expf(acc.x - mx); e.y = expf(acc.y - mx);
                e.z = expf(acc.z - mx); e.w = expf(acc.w - mx);
                float sm = e.x + e.y + e.z + e.w;
                #pragma unroll
                for (int m = 1; m < 16; m <<= 1) sm += __shfl_xor(sm, m);
                float coef = s_state[s] / sm;
                oacc.x = fmaf(coef, e.x, oacc.x); oacc.y = fmaf(coef, e.y, oacc.y);
                oacc.z = fmaf(coef, e.z, oacc.z); oacc.w = fmaf(coef, e.w, oacc.w);
            }
            if (dq == 0) {
                float* dst = isO ? &s_opart[w4][0] : &s_npart[w4][0];
                dst[o4 * 4 + 0] = oacc.x; dst[o4 * 4 + 1] = oacc.y;
                dst[o4 * 4 + 2] = oacc.z; dst[o4 * 4 + 3] = oacc.w;
            }
        }
        __syncthreads();
        if (wave == 0) {
            float o = s_opart[0][lane] + s_opart[1][lane] + s_opart[2][lane] + s_opart[3][lane];
            out[((size_t)b * cT + t) * cNO + lane] = o;
        } else if (wave == 1) {
            s_nstate[lane] = s_npart[0][lane] + s_npart[1][lane] + s_npart[2][lane] + s_npart[3][lane];
        } else if (wave == 2) {
            float p = s_ptr[lane];
            float sd = (lane < cK - 1) ? s_ptr[lane + 1] : 0.f;
            float pop = s_pop;
            float pp = pop * sd + (1.f - pop) * p;
            s_ptr2[lane] = (pop > cTH) ? pp : p;
        }
        __syncthreads();
        if (wave == 0) {
            float p2 = s_ptr2[lane];
            float su = (lane > 0) ? s_ptr2[lane - 1] : 0.f;
            float push = s_push;
            float pp = push * su + (1.f - push) * p2;
            s_w[lane] = pp;
            s_ptr[lane] = (push > cTH) ? pp : p2;
        } else if (wave == 1) {
            s_state[lane] = s_nstate[lane];
        }
        __syncthreads();
        if (s_push > cTH) {
            for (int idx = tid; idx < cK * cD; idx += 512) {
                int k = idx >> 6, d = idx & 63;
                float w = s_w[k];
                s_content[k][d] = s_content[k][d] * (1.f - w) + s_pushv[d] * w;
            }
        }
        __syncthreads();
    }
}
} // namespace

extern "C" void kernel_launch(void* const* d_in, const int* in_sizes, int n_in,
                              void* d_out, int out_size, void* d_ws, size_t ws_size,
                              hipStream_t stream) {
    const int*   seq = (const int*)d_in[0];
    const float* Tm  = (const float*)d_in[1];
    const float* Om  = (const float*)d_in[2];
    const float* pg  = (const float*)d_in[3];
    const float* qg  = (const float*)d_in[4];
    const float* pv  = (const float*)d_in[5];
    const float* il  = (const float*)d_in[6];
    float* o = (float*)d_out;

    const size_t stbuf_bytes  = (size_t)NTASK * 128 * sizeof(float);   // 8 MB
    const size_t counts_off   = stbuf_bytes;
    const size_t offsets_off  = counts_off + 128 * sizeof(int);
    const size_t cursor_off   = offsets_off + 132 * sizeof(int);
    const size_t tasks_off    = cursor_off + 128 * sizeof(int);
    const size_t cnt_off      = tasks_off + (size_t)NTASK * sizeof(int);
    const size_t gpart_off    = cnt_off + (size_t)NTASK * sizeof(int);
    const size_t need         = gpart_off + (size_t)cB * 2 * NSPLIT * 128 * sizeof(float);

    if (ws_size < need) {
        hipLaunchKernelGGL(fpt_mono, dim3(cB), dim3(512), 0, stream,
                           seq, Tm, Om, pg, qg, pv, il, o);
        return;
    }

    float* stbuf  = (float*)d_ws;
    int* counts   = (int*)((char*)d_ws + counts_off);
    int* offsets  = (int*)((char*)d_ws + offsets_off);
    int* cursor   = (int*)((char*)d_ws + cursor_off);
    int* tasks    = (int*)((char*)d_ws + tasks_off);
    int* cnt      = (int*)((char*)d_ws + cnt_off);
    float* gpart  = (float*)((char*)d_ws + gpart_off);

    hipMemsetAsync(counts, 0, 128 * sizeof(int), stream);
    hipMemsetAsync(cnt, 0, (size_t)NTASK * sizeof(int), stream);
    hipLaunchKernelGGL(k_count,   dim3(NTASK / 256), dim3(256), 0, stream, seq, counts);
    hipLaunchKernelGGL(k_scan,    dim3(1),           dim3(64),  0, stream, counts, offsets, cursor);
    hipLaunchKernelGGL(k_scatter, dim3(NTASK / 256), dim3(256), 0, stream, seq, cursor, tasks);
    hipLaunchKernelGGL(p1_kernel, dim3(cB * NSPLIT), dim3(256), 0, stream,
                       seq, Tm, pg, qg, pv, il, stbuf, cnt, gpart);
    hipLaunchKernelGGL(p2_kernel, dim3(256), dim3(512), 0, stream, Om, stbuf, offsets, tasks, o);
}

// Round 15
// 2689.065 us; speedup vs baseline: 1.3174x; 1.0337x over previous
//
#include <hip/hip_runtime.h>
#include <math.h>

namespace {
constexpr int cS = 64, cI = 128, cNO = 64, cK = 64, cD = 64, cB = 64, cT = 256;
constexpr float cTH = 0.01f;
constexpr int NTASK = cB * cT;
constexpr int NSPLIT = 8;                  // WGs per sequence (empirical optimum)
typedef float vf4 __attribute__((ext_vector_type(4)));

__device__ inline void st_agent(float* p, float v) {
    __hip_atomic_store(p, v, __ATOMIC_RELAXED, __HIP_MEMORY_SCOPE_AGENT);
}
__device__ inline float ld_agent(const float* p) {
    return __hip_atomic_load(p, __ATOMIC_RELAXED, __HIP_MEMORY_SCOPE_AGENT);
}

// ====== Phase 1: recurrence, 8 WGs/seq x 256 thr, 2 WGs/CU (cross-seq TLP) ======
__global__ __launch_bounds__(256, 2)
void p1_kernel(const int* __restrict__ seq,
               const float* __restrict__ Tm,     // (S,I,D,S)
               const float* __restrict__ pgate,  // (S,I,1)
               const float* __restrict__ qgate,  // (S,I,1)
               const float* __restrict__ pval,   // (S,I,D)
               const float* __restrict__ initl,  // (S,)
               float* __restrict__ stbuf,        // (B*T,128)
               int* __restrict__ cnt,            // (B*T) zeroed per launch
               float* __restrict__ gpart)        // (B,2,8,128)
{
    const int b  = blockIdx.x >> 3;
    const int jw = blockIdx.x & 7;
    const int tid = threadIdx.x;
    const int wave = tid >> 6, lane = tid & 63;
    const int dq = lane >> 4, o4 = lane & 15;

    __shared__ float s_state[cS], s_stack[cD], s_pushv[cD], s_pvpart[cD];
    __shared__ float s_ptr[cK], s_w[cK];
    __shared__ float s_content[cK][cD];
    __shared__ float s_redA[4][64], s_redB[4][64], s_npart[4][64];
    __shared__ int   s_seq[cT];
    __shared__ float s_push, s_pop;

    if (wave == 0) {
        float v = initl[lane];
        float m = v;
        #pragma unroll
        for (int sh = 1; sh < 64; sh <<= 1) m = fmaxf(m, __shfl_xor(m, sh));
        float e = expf(v - m);
        float s = e;
        #pragma unroll
        for (int sh = 1; sh < 64; sh <<= 1) s += __shfl_xor(s, sh);
        s_state[lane] = e / s;
    } else if (wave == 1) {
        s_ptr[lane] = (lane == 0) ? 1.0f : 0.0f;
    }
    for (int i = tid; i < cK * cD; i += 256) (&s_content[0][0])[i] = 0.f;
    s_seq[tid] = seq[b * cT + tid];
    __syncthreads();

    for (int t = 0; t < cT; ++t) {
        const int inp = s_seq[t];

        // ---- A1: stack_top partials (16 k-rows/wave) + push_v partials (2 s-rows/wave) ----
        {
            float accA = 0.f;
            #pragma unroll
            for (int j = 0; j < 16; ++j) {
                int k = wave * 16 + j;
                accA += s_ptr[k] * s_content[k][lane];
            }
            float accB = 0.f;
            #pragma unroll
            for (int j = 0; j < 2; ++j) {
                int k = jw * 8 + wave * 2 + j;
                accB += s_state[k] * pval[((size_t)k * cI + inp) * cD + lane];
            }
            s_redA[wave][lane] = accA;
            s_redB[wave][lane] = accB;
        }
        __syncthreads();

        // ---- A2: finalize stack_top; gates; stash pv partial; publish stbuf ----
        float* sb = stbuf + (size_t)(b * cT + t) * 128;
        if (wave == 0) {
            float a = s_redA[0][lane] + s_redA[1][lane] + s_redA[2][lane] + s_redA[3][lane];
            s_stack[lane] = a;
            if (jw == 0) { sb[lane] = a; sb[64 + lane] = s_state[lane]; }
        } else if (wave == 1) {
            s_pvpart[lane] = s_redB[0][lane] + s_redB[1][lane] + s_redB[2][lane] + s_redB[3][lane];
        } else if (wave == 2) {
            float v = pgate[lane * cI + inp] * s_state[lane];
            #pragma unroll
            for (int sh = 1; sh < 64; sh <<= 1) v += __shfl_xor(v, sh);
            if (lane == 0) s_push = 1.0f / (1.0f + expf(-v));
        } else {
            float v = qgate[lane * cI + inp] * s_state[lane];
            #pragma unroll
            for (int sh = 1; sh < 64; sh <<= 1) v += __shfl_xor(v, sh);
            if (lane == 0) s_pop = 1.0f / (1.0f + expf(-v));
        }
        __syncthreads();

        // ---- B: this wave's 2 T-rows (32 float4 loads in flight) ----
        {
            float xs[16];
            #pragma unroll
            for (int i = 0; i < 16; ++i) xs[i] = s_stack[dq * 16 + i];

            const int sA = jw * 8 + wave * 2;
            const int sB = sA + 1;
            const vf4* rpA = reinterpret_cast<const vf4*>(
                Tm + (size_t)(sA * cI + inp) * (cD * cS)) + o4;
            const vf4* rpB = reinterpret_cast<const vf4*>(
                Tm + (size_t)(sB * cI + inp) * (cD * cS)) + o4;
            vf4 va[16], vb[16];
            #pragma unroll
            for (int i = 0; i < 16; ++i) {
                va[i] = rpA[(dq * 16 + i) * 16];
                vb[i] = rpB[(dq * 16 + i) * 16];
            }
            vf4 aA, aB;
            aA.x = 0.f; aA.y = 0.f; aA.z = 0.f; aA.w = 0.f;
            aB.x = 0.f; aB.y = 0.f; aB.z = 0.f; aB.w = 0.f;
            #pragma unroll
            for (int i = 0; i < 16; ++i) {
                float x = xs[i];
                aA.x = fmaf(x, va[i].x, aA.x); aA.y = fmaf(x, va[i].y, aA.y);
                aA.z = fmaf(x, va[i].z, aA.z); aA.w = fmaf(x, va[i].w, aA.w);
                aB.x = fmaf(x, vb[i].x, aB.x); aB.y = fmaf(x, vb[i].y, aB.y);
                aB.z = fmaf(x, vb[i].z, aB.z); aB.w = fmaf(x, vb[i].w, aB.w);
            }
            #pragma unroll
            for (int m = 16; m < 64; m <<= 1) {
                aA.x += __shfl_xor(aA.x, m); aA.y += __shfl_xor(aA.y, m);
                aA.z += __shfl_xor(aA.z, m); aA.w += __shfl_xor(aA.w, m);
                aB.x += __shfl_xor(aB.x, m); aB.y += __shfl_xor(aB.y, m);
                aB.z += __shfl_xor(aB.z, m); aB.w += __shfl_xor(aB.w, m);
            }
            float mA = fmaxf(fmaxf(aA.x, aA.y), fmaxf(aA.z, aA.w));
            float mB = fmaxf(fmaxf(aB.x, aB.y), fmaxf(aB.z, aB.w));
            #pragma unroll
            for (int m = 1; m < 16; m <<= 1) {
                mA = fmaxf(mA, __shfl_xor(mA, m));
                mB = fmaxf(mB, __shfl_xor(mB, m));
            }
            vf4 eA, eB;
            eA.x = expf(aA.x - mA); eA.y = expf(aA.y - mA);
            eA.z = expf(aA.z - mA); eA.w = expf(aA.w - mA);
            eB.x = expf(aB.x - mB); eB.y = expf(aB.y - mB);
            eB.z = expf(aB.z - mB); eB.w = expf(aB.w - mB);
            float smA = eA.x + eA.y + eA.z + eA.w;
            float smB = eB.x + eB.y + eB.z + eB.w;
            #pragma unroll
            for (int m = 1; m < 16; m <<= 1) {
                smA += __shfl_xor(smA, m);
                smB += __shfl_xor(smB, m);
            }
            float cA = s_state[sA] / smA;
            float cB = s_state[sB] / smB;
            vf4 nacc;
            nacc.x = cA * eA.x + cB * eB.x;
            nacc.y = cA * eA.y + cB * eB.y;
            nacc.z = cA * eA.z + cB * eB.z;
            nacc.w = cA * eA.w + cB * eB.w;
            if (dq == 0) {
                s_npart[wave][o4 * 4 + 0] = nacc.x;
                s_npart[wave][o4 * 4 + 1] = nacc.y;
                s_npart[wave][o4 * 4 + 2] = nacc.z;
                s_npart[wave][o4 * 4 + 3] = nacc.w;
            }
        }
        __syncthreads();

        // ---- C: wave0 = publish/flag/poll/combine; wave1 = pointer pop+push ----
        if (wave == 0) {
            float* gq = gpart + ((size_t)(b * 2 + (t & 1)) * NSPLIT + jw) * 128;
            float np = s_npart[0][lane] + s_npart[1][lane] + s_npart[2][lane] + s_npart[3][lane];
            st_agent(gq + lane, np);
            st_agent(gq + 64 + lane, s_pvpart[lane]);
            asm volatile("s_waitcnt vmcnt(0)" ::: "memory");
            int* c = cnt + b * cT + t;
            if (lane == 0)
                __hip_atomic_fetch_add(c, 1, __ATOMIC_RELAXED, __HIP_MEMORY_SCOPE_AGENT);
            while (__hip_atomic_load(c, __ATOMIC_RELAXED, __HIP_MEMORY_SCOPE_AGENT) < NSPLIT) {}
            const float* gb = gpart + (size_t)(b * 2 + (t & 1)) * NSPLIT * 128;
            float ns = 0.f, pvs = 0.f;
            #pragma unroll
            for (int q = 0; q < NSPLIT; ++q) {
                ns  += ld_agent(gb + q * 128 + lane);
                pvs += ld_agent(gb + q * 128 + 64 + lane);
            }
            s_state[lane] = ns;
            s_pushv[lane] = tanhf(pvs);
        } else if (wave == 1) {
            float p  = s_ptr[lane];
            float sd = (lane < cK - 1) ? s_ptr[lane + 1] : 0.f;
            float pop = s_pop;
            float ppo = pop * sd + (1.f - pop) * p;
            float p2  = (pop > cTH) ? ppo : p;
            float su  = __shfl_up(p2, 1);
            if (lane == 0) su = 0.f;
            float push = s_push;
            float ppu = push * su + (1.f - push) * p2;
            s_w[lane] = ppu;
            s_ptr[lane] = (push > cTH) ? ppu : p2;
        }
        __syncthreads();

        // ---- C3: content update (uniform branch, identical across WGs) ----
        if (s_push > cTH) {
            #pragma unroll
            for (int it = 0; it < 16; ++it) {
                int idx = tid + it * 256;
                int k = idx >> 6, d = idx & 63;
                float w = s_w[k];
                s_content[k][d] = s_content[k][d] * (1.f - w) + s_pushv[d] * w;
            }
        }
        __syncthreads();
    }
}

// =================== Binning: group (b,t) tasks by symbol ===================
__global__ void k_count(const int* __restrict__ seq, int* __restrict__ counts) {
    int i = blockIdx.x * 256 + threadIdx.x;
    if (i < NTASK) atomicAdd(&counts[seq[i]], 1);
}
__global__ void k_scan(const int* __restrict__ counts, int* __restrict__ offsets,
                       int* __restrict__ cursor) {
    const int lane = threadIdx.x & 63;
    int c0 = counts[lane], c1 = counts[64 + lane];
    int s0 = c0, s1 = c1;
    #pragma unroll
    for (int m = 1; m < 64; m <<= 1) {
        int t0 = __shfl_up(s0, m);
        int t1 = __shfl_up(s1, m);
        if (lane >= m) { s0 += t0; s1 += t1; }
    }
    int tot0 = __shfl(s0, 63);
    int e0 = s0 - c0;
    int e1 = tot0 + s1 - c1;
    offsets[lane] = e0;       cursor[lane] = e0;
    offsets[64 + lane] = e1;  cursor[64 + lane] = e1;
    if (lane == 63) offsets[128] = tot0 + __shfl(s1, 63);
}
__global__ void k_scatter(const int* __restrict__ seq, int* __restrict__ cursor,
                          int* __restrict__ tasks) {
    int i = blockIdx.x * 256 + threadIdx.x;
    if (i < NTASK) {
        int pos = atomicAdd(&cursor[seq[i]], 1);
        tasks[pos] = i;
    }
}

// ====== Phase 2: output head. LDS-staged O rows, NT loads, 8 tasks/wave ======
__global__ __launch_bounds__(512, 2)
void p2_kernel(const float* __restrict__ Om,      // (S,I,D,NO)
               const float* __restrict__ stbuf,   // (B*T,128)
               const int* __restrict__ offsets,   // (129,)
               const int* __restrict__ tasks,     // (B*T,)
               float* __restrict__ out)           // (B*T,NO)
{
    const int g = blockIdx.x >> 1, h = blockIdx.x & 1;
    const int tid = threadIdx.x, wave = tid >> 6, lane = tid & 63;
    const int dq = lane >> 4, o4 = lane & 15;

    const int beg = offsets[g], end = offsets[g + 1];
    const int n = end - beg, half = (n + 1) >> 1;
    const int hbeg = beg + h * half;
    const int hend = h ? end : (beg + half);
    const int cnt = hend - hbeg;
    if (cnt <= 0) return;
    const int nsweep = (cnt + 63) >> 6;

    __shared__ vf4 sO[2][1024];

    const vf4* O0 = reinterpret_cast<const vf4*>(Om) + (size_t)g * 1024;
    const size_t rowstride = (size_t)cI * 1024;

    for (int sweep = 0; sweep < nsweep; ++sweep) {
        int   tsk[8];
        bool  val[8];
        float stv[8][16];
        float sstate[8];
        vf4   acc[8];
        #pragma unroll
        for (int u = 0; u < 8; ++u) {
            int idx = hbeg + sweep * 64 + (u >> 2) * 32 + wave * 4 + (u & 3);
            bool v = idx < hend;
            val[u] = v;
            int id = tasks[v ? idx : hbeg];
            id = __builtin_amdgcn_readfirstlane(id);
            tsk[u] = id;
            const float* sp = stbuf + (size_t)id * 128;
            #pragma unroll
            for (int i = 0; i < 16; ++i) stv[u][i] = sp[dq * 16 + i];
            sstate[u] = sp[64 + lane];
            acc[u].x = 0.f; acc[u].y = 0.f; acc[u].z = 0.f; acc[u].w = 0.f;
        }

        vf4 r0 = __builtin_nontemporal_load(O0 + (size_t)tid * 2);
        vf4 r1 = __builtin_nontemporal_load(O0 + (size_t)tid * 2 + 1);

        for (int s = 0; s < cS; ++s) {
            sO[s & 1][tid * 2]     = r0;
            sO[s & 1][tid * 2 + 1] = r1;
            __syncthreads();
            if (s + 1 < cS) {
                const vf4* nr = O0 + (size_t)(s + 1) * rowstride;
                r0 = __builtin_nontemporal_load(nr + (size_t)tid * 2);
                r1 = __builtin_nontemporal_load(nr + (size_t)tid * 2 + 1);
            }
            vf4 part[8];
            #pragma unroll
            for (int u = 0; u < 8; ++u) { part[u].x = 0.f; part[u].y = 0.f; part[u].z = 0.f; part[u].w = 0.f; }
            #pragma unroll
            for (int i = 0; i < 16; ++i) {
                vf4 ovi = sO[s & 1][(dq * 16 + i) * 16 + o4];
                #pragma unroll
                for (int u = 0; u < 8; ++u) {
                    float x = stv[u][i];
                    part[u].x = fmaf(x, ovi.x, part[u].x);
                    part[u].y = fmaf(x, ovi.y, part[u].y);
                    part[u].z = fmaf(x, ovi.z, part[u].z);
                    part[u].w = fmaf(x, ovi.w, part[u].w);
                }
            }
            #pragma unroll
            for (int u = 0; u < 8; ++u) {
                vf4 a = part[u];
                #pragma unroll
                for (int m = 16; m < 64; m <<= 1) {
                    a.x += __shfl_xor(a.x, m); a.y += __shfl_xor(a.y, m);
                    a.z += __shfl_xor(a.z, m); a.w += __shfl_xor(a.w, m);
                }
                float mx = fmaxf(fmaxf(a.x, a.y), fmaxf(a.z, a.w));
                #pragma unroll
                for (int m = 1; m < 16; m <<= 1) mx = fmaxf(mx, __shfl_xor(mx, m));
                vf4 e;
                e.x = expf(a.x - mx); e.y = expf(a.y - mx);
                e.z = expf(a.z - mx); e.w = expf(a.w - mx);
                float sm = e.x + e.y + e.z + e.w;
                #pragma unroll
                for (int m = 1; m < 16; m <<= 1) sm += __shfl_xor(sm, m);
                float coef = __shfl(sstate[u], s) / sm;
                acc[u].x = fmaf(coef, e.x, acc[u].x);
                acc[u].y = fmaf(coef, e.y, acc[u].y);
                acc[u].z = fmaf(coef, e.z, acc[u].z);
                acc[u].w = fmaf(coef, e.w, acc[u].w);
            }
        }
        #pragma unroll
        for (int u = 0; u < 8; ++u) {
            if (val[u] && dq == 0) {
                float* op = out + (size_t)tsk[u] * cNO + o4 * 4;
                op[0] = acc[u].x; op[1] = acc[u].y; op[2] = acc[u].z; op[3] = acc[u].w;
            }
        }
    }
}

// =================== Fallback: monolithic (if ws too small) ===================
__global__ __launch_bounds__(512, 1)
void fpt_mono(const int* __restrict__ seq, const float* __restrict__ Tm,
              const float* __restrict__ Om, const float* __restrict__ pgate,
              const float* __restrict__ qgate, const float* __restrict__ pval,
              const float* __restrict__ initl, float* __restrict__ out)
{
    const int b = blockIdx.x;
    const int tid = threadIdx.x;
    const int wave = tid >> 6, lane = tid & 63;
    const int dq = lane >> 4, o4 = lane & 15;

    __shared__ float s_state[cS], s_nstate[cS], s_stack[cD], s_pushv[cD];
    __shared__ float s_ptr[cK], s_ptr2[cK], s_w[cK];
    __shared__ float s_content[cK][cD];
    __shared__ float s_redA[8][64], s_redB[8][64];
    __shared__ float s_opart[4][cNO], s_npart[4][cS];
    __shared__ float s_push, s_pop;

    if (wave == 0) {
        float v = initl[lane];
        float m = v;
        #pragma unroll
        for (int sh = 1; sh < 64; sh <<= 1) m = fmaxf(m, __shfl_xor(m, sh));
        float e = expf(v - m);
        float s = e;
        #pragma unroll
        for (int sh = 1; sh < 64; sh <<= 1) s += __shfl_xor(s, sh);
        s_state[lane] = e / s;
    } else if (wave == 1) s_ptr[lane] = (lane == 0) ? 1.0f : 0.0f;
    for (int idx = tid; idx < cK * cD; idx += 512) (&s_content[0][0])[idx] = 0.0f;
    __syncthreads();

    for (int t = 0; t < cT; ++t) {
        const int inp = seq[b * cT + t];
        {
            float accA = 0.f, accB = 0.f;
            #pragma unroll
            for (int j = 0; j < 8; ++j) {
                int k = wave * 8 + j;
                accA += s_ptr[k] * s_content[k][lane];
                accB += s_state[k] * pval[(k * cI + inp) * cD + lane];
            }
            s_redA[wave][lane] = accA;
            s_redB[wave][lane] = accB;
        }
        __syncthreads();
        if (wave == 0) {
            float a = 0.f;
            #pragma unroll
            for (int g = 0; g < 8; ++g) a += s_redA[g][lane];
            s_stack[lane] = a;
        } else if (wave == 1) {
            float a = 0.f;
            #pragma unroll
            for (int g = 0; g < 8; ++g) a += s_redB[g][lane];
            s_pushv[lane] = tanhf(a);
        } else if (wave == 2) {
            float v = pgate[lane * cI + inp] * s_state[lane];
            #pragma unroll
            for (int sh = 1; sh < 64; sh <<= 1) v += __shfl_xor(v, sh);
            if (lane == 0) s_push = 1.0f / (1.0f + expf(-v));
        } else if (wave == 3) {
            float v = qgate[lane * cI + inp] * s_state[lane];
            #pragma unroll
            for (int sh = 1; sh < 64; sh <<= 1) v += __shfl_xor(v, sh);
            if (lane == 0) s_pop = 1.0f / (1.0f + expf(-v));
        }
        __syncthreads();
        {
            const bool isO = (wave < 4);
            const int w4 = wave & 3;
            const float* Mbase = isO ? Om : Tm;
            float xs[16];
            #pragma unroll
            for (int i = 0; i < 16; ++i) xs[i] = s_stack[dq * 16 + i];
            float4 oacc = make_float4(0.f, 0.f, 0.f, 0.f);
            for (int r = 0; r < 16; ++r) {
                const int s = w4 * 16 + r;
                const float4* rowp =
                    reinterpret_cast<const float4*>(Mbase + (size_t)(s * cI + inp) * (cD * 64)) + o4;
                float4 acc = make_float4(0.f, 0.f, 0.f, 0.f);
                #pragma unroll
                for (int i = 0; i < 16; ++i) {
                    float4 mv = rowp[(dq * 16 + i) * 16];
                    float xd = xs[i];
                    acc.x = fmaf(xd, mv.x, acc.x); acc.y = fmaf(xd, mv.y, acc.y);
                    acc.z = fmaf(xd, mv.z, acc.z); acc.w = fmaf(xd, mv.w, acc.w);
                }
                #pragma unroll
                for (int m = 16; m < 64; m <<= 1) {
                    acc.x += __shfl_xor(acc.x, m); acc.y += __shfl_xor(acc.y, m);
                    acc.z += __shfl_xor(acc.z, m); acc.w += __shfl_xor(acc.w, m);
                }
                float mx = fmaxf(fmaxf(acc.x, acc.y), fmaxf(acc.z, acc.w));
                #pragma unroll
                for (int m = 1; m < 16; m <<= 1) mx = fmaxf(mx, __shfl_xor(mx, m));
                float4 e;
                e.x = expf(acc.x - mx); e.y = expf(acc.y - mx);
                e.z = expf(acc.z - mx); e.w = expf(acc.w - mx);
                float sm = e.x + e.y + e.z + e.w;
                #pragma unroll
                for (int m = 1; m < 16; m <<= 1) sm += __shfl_xor(sm, m);
                float coef = s_state[s] / sm;
                oacc.x = fmaf(coef, e.x, oacc.x); oacc.y = fmaf(coef, e.y, oacc.y);
                oacc.z = fmaf(coef, e.z, oacc.z); oacc.w = fmaf(coef, e.w, oacc.w);
            }
            if (dq == 0) {
                float* dst = isO ? &s_opart[w4][0] : &s_npart[w4][0];
                dst[o4 * 4 + 0] = oacc.x; dst[o4 * 4 + 1] = oacc.y;
                dst[o4 * 4 + 2] = oacc.z; dst[o4 * 4 + 3] = oacc.w;
            }
        }
        __syncthreads();
        if (wave == 0) {
            float o = s_opart[0][lane] + s_opart[1][lane] + s_opart[2][lane] + s_opart[3][lane];
            out[((size_t)b * cT + t) * cNO + lane] = o;
        } else if (wave == 1) {
            s_nstate[lane] = s_npart[0][lane] + s_npart[1][lane] + s_npart[2][lane] + s_npart[3][lane];
        } else if (wave == 2) {
            float p = s_ptr[lane];
            float sd = (lane < cK - 1) ? s_ptr[lane + 1] : 0.f;
            float pop = s_pop;
            float pp = pop * sd + (1.f - pop) * p;
            s_ptr2[lane] = (pop > cTH) ? pp : p;
        }
        __syncthreads();
        if (wave == 0) {
            float p2 = s_ptr2[lane];
            float su = (lane > 0) ? s_ptr2[lane - 1] : 0.f;
            float push = s_push;
            float pp = push * su + (1.f - push) * p2;
            s_w[lane] = pp;
            s_ptr[lane] = (push > cTH) ? pp : p2;
        } else if (wave == 1) {
            s_state[lane] = s_nstate[lane];
        }
        __syncthreads();
        if (s_push > cTH) {
            for (int idx = tid; idx < cK * cD; idx += 512) {
                int k = idx >> 6, d = idx & 63;
                float w = s_w[k];
                s_content[k][d] = s_content[k][d] * (1.f - w) + s_pushv[d] * w;
            }
        }
        __syncthreads();
    }
}
} // namespace

extern "C" void kernel_launch(void* const* d_in, const int* in_sizes, int n_in,
                              void* d_out, int out_size, void* d_ws, size_t ws_size,
                              hipStream_t stream) {
    const int*   seq = (const int*)d_in[0];
    const float* Tm  = (const float*)d_in[1];
    const float* Om  = (const float*)d_in[2];
    const float* pg  = (const float*)d_in[3];
    const float* qg  = (const float*)d_in[4];
    const float* pv  = (const float*)d_in[5];
    const float* il  = (const float*)d_in[6];
    float* o = (float*)d_out;

    const size_t stbuf_bytes  = (size_t)NTASK * 128 * sizeof(float);   // 8 MB
    const size_t counts_off   = stbuf_bytes;
    const size_t offsets_off  = counts_off + 128 * sizeof(int);
    const size_t cursor_off   = offsets_off + 132 * sizeof(int);
    const size_t tasks_off    = cursor_off + 128 * sizeof(int);
    const size_t cnt_off      = tasks_off + (size_t)NTASK * sizeof(int);
    const size_t gpart_off    = cnt_off + (size_t)NTASK * sizeof(int);
    const size_t need         = gpart_off + (size_t)cB * 2 * NSPLIT * 128 * sizeof(float);

    if (ws_size < need) {
        hipLaunchKernelGGL(fpt_mono, dim3(cB), dim3(512), 0, stream,
                           seq, Tm, Om, pg, qg, pv, il, o);
        return;
    }

    float* stbuf  = (float*)d_ws;
    int* counts   = (int*)((char*)d_ws + counts_off);
    int* offsets  = (int*)((char*)d_ws + offsets_off);
    int* cursor   = (int*)((char*)d_ws + cursor_off);
    int* tasks    = (int*)((char*)d_ws + tasks_off);
    int* cnt      = (int*)((char*)d_ws + cnt_off);
    float* gpart  = (float*)((char*)d_ws + gpart_off);

    hipMemsetAsync(counts, 0, 128 * sizeof(int), stream);
    hipMemsetAsync(cnt, 0, (size_t)NTASK * sizeof(int), stream);
    hipLaunchKernelGGL(k_count,   dim3(NTASK / 256), dim3(256), 0, stream, seq, counts);
    hipLaunchKernelGGL(k_scan,    dim3(1),           dim3(64),  0, stream, counts, offsets, cursor);
    hipLaunchKernelGGL(k_scatter, dim3(NTASK / 256), dim3(256), 0, stream, seq, cursor, tasks);
    hipLaunchKernelGGL(p1_kernel, dim3(cB * NSPLIT), dim3(256), 0, stream,
                       seq, Tm, pg, qg, pv, il, stbuf, cnt, gpart);
    hipLaunchKernelGGL(p2_kernel, dim3(256), dim3(512), 0, stream, Om, stbuf, offsets, tasks, o);
}